// Round 3
// baseline (459.300 us; speedup 1.0000x reference)
//
#include <hip/hip_runtime.h>
#include <float.h>
#include <math.h>

#define DEV_INLINE __device__ __forceinline__

// ---------------- problem constants ----------------
// B=64, C_IN=8, L=1024, D=64, K=256, E=512, BETA=0.25, EPS_LIP=0.01

// ---------------- ws layout (float offsets) ----------------
// small region (shared by both paths)
static constexpr size_t F_CN    = 0;       // 512   : |c_e|^2
static constexpr size_t F_LVP   = 512;     // 256   : lv partials [4][B]
static constexpr size_t F_TGT   = 768;     // 64    : log-sum targets
static constexpr size_t F_ACC   = 832;     // 16    : [0]=vq [1]=lip [2]=crv
static constexpr size_t F_CODES = 848;     // 16384 : codes [B][K] (int)
static constexpr size_t F_DIST  = 17232;   // 4096  : dist [B][B]
static constexpr size_t F_PBEST = 21328;   // 131072: per-tile best dist [8][B][K]
static constexpr size_t F_PIDX  = 152400;  // 131072: per-tile best idx (int)
static constexpr size_t F_SMALL = 283472;

// path A (fused decoder, batch 128): needs 19,682,128 floats (~78.7 MB)
static constexpr size_t A_YRAW = 283472;            // 524288
static constexpr size_t A_Z2   = 807760;            // 2097152 : [128][64][256] zq|zq2
static constexpr size_t A_H1   = 2904912;           // 8388608 : [128][128][512]; enc temps live here first
static constexpr size_t A_H2   = 11293520;          // 8388608 : [128][64][1024]; pre-VQ z lives here first
static constexpr size_t A_END  = 19682128;

// path B (split decoder): needs 11,293,520 floats (~45.2 MB)
static constexpr size_t B_YRAW = 283472;            // 524288
static constexpr size_t B_ZQ   = 807760;            // 1048576 : zq [64][64][256]
static constexpr size_t B_Z    = 1856336;           // 1048576 : z, then zq2 (in-place)
static constexpr size_t B_H2   = 2904912;           // 4194304 : h2 [64][64][1024]
static constexpr size_t B_BIG  = 7099216;           // 4194304 : h1e|h2e (enc), then dec h1
static constexpr size_t B_END  = 11293520;

// out layout: y [64*8*1024] | lv_loss [64*64] | vq_loss | smoothness
static constexpr size_t OUT_LV = 524288;

// ---------------- reduction helpers ----------------
DEV_INLINE float waveReduceSum(float v) {
    #pragma unroll
    for (int m = 32; m > 0; m >>= 1) v += __shfl_xor(v, m, 64);
    return v;
}

// blockDim.x == 256. Safe to call repeatedly with the same buf.
DEV_INLINE float blockReduceSum256(float v, float* buf) {
    __syncthreads();
    v = waveReduceSum(v);
    if ((threadIdx.x & 63) == 0) buf[threadIdx.x >> 6] = v;
    __syncthreads();
    return (buf[0] + buf[1]) + (buf[2] + buf[3]);
}

// ---------------- preamble: acc zero + cnorm + tgt ----------------
__global__ __launch_bounds__(256)
void preamble_kernel(const float* __restrict__ x, const float* __restrict__ cb,
                     float* __restrict__ cnorm, float* __restrict__ tgt,
                     float* __restrict__ acc) {
    const int blk = blockIdx.x;
    if (blk < 64) {                       // tgt[b] = log(sum x[b,0,:] + 1e-7)
        __shared__ float red[4];
        const float* __restrict__ xb = x + (size_t)blk * 8 * 1024;
        float s = 0.f;
        for (int t = threadIdx.x; t < 1024; t += 256) s += xb[t];
        const float tot = blockReduceSum256(s, red);
        if (threadIdx.x == 0) tgt[blk] = logf(tot + 1e-7f);
    } else if (blk < 66) {                // cnorm
        const int e = (blk - 64) * 256 + threadIdx.x;
        const float* __restrict__ c = cb + (size_t)e * 64;
        float s = 0.f;
        #pragma unroll
        for (int d = 0; d < 64; ++d) s = fmaf(c[d], c[d], s);
        cnorm[e] = s;
    } else {
        if (threadIdx.x < 16) acc[threadIdx.x] = 0.f;
    }
}

// ---------------- conv kernels (OG output channels per block) ----------------
// stride-2, k=4, pad=1. grid (Cout/OG, B, LOUT/256). w layout [Cout][CIN][4].
// out[t] = sum_i sum_dk w[o][i][dk] * x[i][2t-1+dk]
template<int CIN, int LIN, int LOUT, int OG, bool RELU>
__global__ __launch_bounds__(256)
void conv_s2k4(const float* __restrict__ in, const float* __restrict__ w,
               const float* __restrict__ bias, float* __restrict__ out) {
    const int og = blockIdx.x;
    const int b  = blockIdx.y;
    const int t  = blockIdx.z * 256 + threadIdx.x;
    __shared__ __align__(16) float4 wsm[OG * CIN];
    const float4* __restrict__ wg = reinterpret_cast<const float4*>(w) + (size_t)og * OG * CIN;
    for (int idx = threadIdx.x; idx < OG * CIN; idx += 256) wsm[idx] = wg[idx];
    __syncthreads();
    const float* __restrict__ inb = in + (size_t)b * CIN * LIN;
    float acc[OG];
    #pragma unroll
    for (int oo = 0; oo < OG; ++oo) acc[oo] = 0.f;
    const int p0 = 2 * t - 1;
    const bool v0 = (t > 0);
    const bool v3 = (t < LOUT - 1);
    const int q0 = v0 ? p0 : 0;
    const int q3 = v3 ? p0 + 3 : 0;
    for (int i = 0; i < CIN; ++i) {
        const float* __restrict__ row = inb + (size_t)i * LIN;
        float x0 = row[q0]; x0 = v0 ? x0 : 0.f;
        const float x1 = row[p0 + 1];
        const float x2 = row[p0 + 2];
        float x3 = row[q3]; x3 = v3 ? x3 : 0.f;
        #pragma unroll
        for (int oo = 0; oo < OG; ++oo) {
            const float4 wv = wsm[oo * CIN + i];
            acc[oo] = fmaf(x0, wv.x, acc[oo]);
            acc[oo] = fmaf(x1, wv.y, acc[oo]);
            acc[oo] = fmaf(x2, wv.z, acc[oo]);
            acc[oo] = fmaf(x3, wv.w, acc[oo]);
        }
    }
    const int Cout = gridDim.x * OG;
    float* __restrict__ outb = out + ((size_t)b * Cout + og * OG) * LOUT + t;
    #pragma unroll
    for (int oo = 0; oo < OG; ++oo) {
        float v = acc[oo] + bias[og * OG + oo];
        if (RELU) v = fmaxf(v, 0.f);
        outb[(size_t)oo * LOUT] = v;
    }
}

// stride-1, k=3, pad=1. grid (Cout/OG, B, LIN/256). w layout [Cout][CIN][3].
template<int CIN, int LIN, int OG, bool RELU>
__global__ __launch_bounds__(256)
void conv_s1k3(const float* __restrict__ in, const float* __restrict__ w,
               const float* __restrict__ bias, float* __restrict__ out) {
    const int og = blockIdx.x;
    const int b  = blockIdx.y;
    const int t  = blockIdx.z * 256 + threadIdx.x;
    __shared__ __align__(16) float4 wsm[OG * CIN];
    for (int idx = threadIdx.x; idx < OG * CIN; idx += 256) {
        const float* __restrict__ src = w + ((size_t)og * OG * CIN + idx) * 3;
        wsm[idx] = make_float4(src[0], src[1], src[2], 0.f);
    }
    __syncthreads();
    const float* __restrict__ inb = in + (size_t)b * CIN * LIN;
    float acc[OG];
    #pragma unroll
    for (int oo = 0; oo < OG; ++oo) acc[oo] = 0.f;
    const bool vl = (t > 0), vr = (t < LIN - 1);
    const int ql = vl ? t - 1 : 0, qr = vr ? t + 1 : 0;
    for (int i = 0; i < CIN; ++i) {
        const float* __restrict__ row = inb + (size_t)i * LIN;
        float x0 = row[ql]; x0 = vl ? x0 : 0.f;
        const float x1 = row[t];
        float x2 = row[qr]; x2 = vr ? x2 : 0.f;
        #pragma unroll
        for (int oo = 0; oo < OG; ++oo) {
            const float4 wv = wsm[oo * CIN + i];
            acc[oo] = fmaf(x0, wv.x, acc[oo]);
            acc[oo] = fmaf(x1, wv.y, acc[oo]);
            acc[oo] = fmaf(x2, wv.z, acc[oo]);
        }
    }
    const int Cout = gridDim.x * OG;
    float* __restrict__ outb = out + ((size_t)b * Cout + og * OG) * LIN + t;
    #pragma unroll
    for (int oo = 0; oo < OG; ++oo) {
        float v = acc[oo] + bias[og * OG + oo];
        if (RELU) v = fmaxf(v, 0.f);
        outb[(size_t)oo * LIN] = v;
    }
}

// ConvTranspose1d (k=4, s=2, p=1) gather. grid (Cout/OG, B, LIN/256).
// out[2te]   = b + sum_i x[i][te-1]*w[i][0] + x[i][te]*w[i][2]
// out[2te+1] = b + sum_i x[i][te]*w[i][1]   + x[i][te+1]*w[i][3]
template<int CIN, int LIN, int OG, bool RELU>
__global__ __launch_bounds__(256)
void convT_tiled(const float* __restrict__ in, const float* __restrict__ w,
                 const float* __restrict__ bias, float* __restrict__ out) {
    const int og = blockIdx.x;
    const int b  = blockIdx.y;
    const int te = blockIdx.z * 256 + threadIdx.x;
    __shared__ __align__(16) float4 wsm[OG * CIN];
    const float4* __restrict__ wg = reinterpret_cast<const float4*>(w) + (size_t)og * OG * CIN;
    for (int idx = threadIdx.x; idx < OG * CIN; idx += 256) wsm[idx] = wg[idx];
    __syncthreads();
    const float* __restrict__ inb = in + (size_t)b * CIN * LIN;
    float ae[OG], ao[OG];
    #pragma unroll
    for (int oo = 0; oo < OG; ++oo) { ae[oo] = 0.f; ao[oo] = 0.f; }
    const bool vp = (te > 0), vn = (te < LIN - 1);
    const int qp = vp ? te - 1 : 0, qn = vn ? te + 1 : 0;
    for (int i = 0; i < CIN; ++i) {
        const float* __restrict__ row = inb + (size_t)i * LIN;
        float xp = row[qp]; xp = vp ? xp : 0.f;
        const float xc = row[te];
        float xn = row[qn]; xn = vn ? xn : 0.f;
        #pragma unroll
        for (int oo = 0; oo < OG; ++oo) {
            const float4 wv = wsm[oo * CIN + i];
            ae[oo] = fmaf(xp, wv.x, ae[oo]);
            ae[oo] = fmaf(xc, wv.z, ae[oo]);
            ao[oo] = fmaf(xc, wv.y, ao[oo]);
            ao[oo] = fmaf(xn, wv.w, ao[oo]);
        }
    }
    const int Cout = gridDim.x * OG;
    float2* __restrict__ outb =
        reinterpret_cast<float2*>(out + ((size_t)b * Cout + og * OG) * (2 * LIN)) + te;
    #pragma unroll
    for (int oo = 0; oo < OG; ++oo) {
        const float bb = bias[og * OG + oo];
        float ve = ae[oo] + bb, vo = ao[oo] + bb;
        if (RELU) { ve = fmaxf(ve, 0.f); vo = fmaxf(vo, 0.f); }
        outb[(size_t)oo * LIN] = make_float2(ve, vo);
    }
}

// final conv (64->8, k=3, s=1, p=1), both streams per block (fused path).
// h2a = clean stream (store y_raw), h2b = perturbed (lip += (yA-yB)^2; bias cancels).
__global__ __launch_bounds__(256)
void convd3_both(const float* __restrict__ h2a, const float* __restrict__ h2b,
                 const float* __restrict__ w, const float* __restrict__ bias,
                 float* __restrict__ yraw_out, float* __restrict__ lip_acc) {
    const int b = blockIdx.y;
    const int t = blockIdx.x * 256 + threadIdx.x;
    __shared__ __align__(16) float4 wsm[8 * 64];
    __shared__ float red[4];
    for (int idx = threadIdx.x; idx < 512; idx += 256) {
        const float* __restrict__ src = w + (size_t)idx * 3;
        wsm[idx] = make_float4(src[0], src[1], src[2], 0.f);
    }
    __syncthreads();
    const float* __restrict__ inA = h2a + (size_t)b * 65536;
    const float* __restrict__ inB = h2b + (size_t)b * 65536;
    float accA[8], accB[8];
    #pragma unroll
    for (int oo = 0; oo < 8; ++oo) { accA[oo] = 0.f; accB[oo] = 0.f; }
    const bool vl = (t > 0), vr = (t < 1023);
    const int ql = vl ? t - 1 : 0, qr = vr ? t + 1 : 0;
    for (int i = 0; i < 64; ++i) {
        const float* __restrict__ ra = inA + (size_t)i * 1024;
        const float* __restrict__ rb = inB + (size_t)i * 1024;
        float a0 = ra[ql]; a0 = vl ? a0 : 0.f;
        const float a1 = ra[t];
        float a2 = ra[qr]; a2 = vr ? a2 : 0.f;
        float b0 = rb[ql]; b0 = vl ? b0 : 0.f;
        const float b1 = rb[t];
        float b2 = rb[qr]; b2 = vr ? b2 : 0.f;
        #pragma unroll
        for (int oo = 0; oo < 8; ++oo) {
            const float4 wv = wsm[oo * 64 + i];
            accA[oo] = fmaf(a0, wv.x, accA[oo]);
            accA[oo] = fmaf(a1, wv.y, accA[oo]);
            accA[oo] = fmaf(a2, wv.z, accA[oo]);
            accB[oo] = fmaf(b0, wv.x, accB[oo]);
            accB[oo] = fmaf(b1, wv.y, accB[oo]);
            accB[oo] = fmaf(b2, wv.z, accB[oo]);
        }
    }
    const size_t obase = (size_t)b * 8192 + t;
    float lpart = 0.f;
    #pragma unroll
    for (int oo = 0; oo < 8; ++oo) {
        yraw_out[obase + (size_t)oo * 1024] = accA[oo] + bias[oo];
        const float d = accA[oo] - accB[oo];
        lpart = fmaf(d, d, lpart);
    }
    const float tot = blockReduceSum256(lpart, red);
    if (threadIdx.x == 0) atomicAdd(lip_acc, tot);
}

// split-path final conv. LIP=false: store y_raw. LIP=true: accumulate (y2-yref)^2.
template<bool LIP>
__global__ __launch_bounds__(256)
void convd3_tiled(const float* __restrict__ in, const float* __restrict__ w,
                  const float* __restrict__ bias, float* __restrict__ yraw_out,
                  const float* __restrict__ yraw_ref, float* __restrict__ lip_acc) {
    const int b = blockIdx.y;
    const int t = blockIdx.x * 256 + threadIdx.x;
    __shared__ __align__(16) float4 wsm[8 * 64];
    __shared__ float red[4];
    for (int idx = threadIdx.x; idx < 512; idx += 256) {
        const float* __restrict__ src = w + (size_t)idx * 3;
        wsm[idx] = make_float4(src[0], src[1], src[2], 0.f);
    }
    __syncthreads();
    const float* __restrict__ inb = in + (size_t)b * 65536;
    float acc[8];
    #pragma unroll
    for (int oo = 0; oo < 8; ++oo) acc[oo] = 0.f;
    const bool vl = (t > 0), vr = (t < 1023);
    const int ql = vl ? t - 1 : 0, qr = vr ? t + 1 : 0;
    for (int i = 0; i < 64; ++i) {
        const float* __restrict__ row = inb + (size_t)i * 1024;
        float x0 = row[ql]; x0 = vl ? x0 : 0.f;
        const float x1 = row[t];
        float x2 = row[qr]; x2 = vr ? x2 : 0.f;
        #pragma unroll
        for (int oo = 0; oo < 8; ++oo) {
            const float4 wv = wsm[oo * 64 + i];
            acc[oo] = fmaf(x0, wv.x, acc[oo]);
            acc[oo] = fmaf(x1, wv.y, acc[oo]);
            acc[oo] = fmaf(x2, wv.z, acc[oo]);
        }
    }
    const size_t obase = (size_t)b * 8192 + t;
    if (!LIP) {
        #pragma unroll
        for (int oo = 0; oo < 8; ++oo)
            yraw_out[obase + (size_t)oo * 1024] = acc[oo] + bias[oo];
    } else {
        float lpart = 0.f;
        #pragma unroll
        for (int oo = 0; oo < 8; ++oo) {
            const float d = (acc[oo] + bias[oo]) - yraw_ref[obase + (size_t)oo * 1024];
            lpart = fmaf(d, d, lpart);
        }
        const float tot = blockReduceSum256(lpart, red);
        if (threadIdx.x == 0) atomicAdd(lip_acc, tot);
    }
}

// ---------------- VQ ----------------
// grid (8 code-tiles, B). thread = k. z[b,:,k] in regs; 64-code tile in LDS.
__global__ __launch_bounds__(256)
void vq_dist_kernel(const float* __restrict__ z, const float* __restrict__ cb,
                    const float* __restrict__ cnorm,
                    float* __restrict__ pbest, int* __restrict__ pidx) {
    const int tile = blockIdx.x;
    const int b = blockIdx.y;
    const int k = threadIdx.x;
    __shared__ __align__(16) float ct[64 * 64];
    __shared__ float cn[64];
    float zr[64];
    #pragma unroll
    for (int d = 0; d < 64; ++d) zr[d] = z[((size_t)(b * 64 + d)) * 256 + k];
    const float* __restrict__ src = cb + (size_t)tile * 64 * 64;
    for (int idx = threadIdx.x; idx < 4096; idx += 256) ct[idx] = src[idx];
    if (threadIdx.x < 64) cn[threadIdx.x] = cnorm[tile * 64 + threadIdx.x];
    __syncthreads();
    float best = FLT_MAX; int bi = 0;
    for (int e = 0; e < 64; ++e) {
        const float4* __restrict__ c4p = reinterpret_cast<const float4*>(ct + e * 64);
        float d0 = 0.f, d1 = 0.f, d2 = 0.f, d3 = 0.f;
        #pragma unroll
        for (int q = 0; q < 16; ++q) {
            const float4 c4 = c4p[q];
            d0 = fmaf(zr[4 * q + 0], c4.x, d0);
            d1 = fmaf(zr[4 * q + 1], c4.y, d1);
            d2 = fmaf(zr[4 * q + 2], c4.z, d2);
            d3 = fmaf(zr[4 * q + 3], c4.w, d3);
        }
        const float dist = cn[e] - 2.f * ((d0 + d1) + (d2 + d3));
        if (dist < best) { best = dist; bi = tile * 64 + e; } // strict < : first-min
    }
    pbest[((size_t)tile * 64 + b) * 256 + k] = best;
    pidx [((size_t)tile * 64 + b) * 256 + k] = bi;
}

// combine tiles; write codes, zq, zq2 (= codebook + 0.01*noise), vq partial.
__global__ __launch_bounds__(256)
void vq_combine_kernel(const float* __restrict__ z, const float* __restrict__ cb,
                       const float* __restrict__ pbest, const int* __restrict__ pidx,
                       const float* __restrict__ nz,
                       int* __restrict__ codes, float* __restrict__ zq,
                       float* __restrict__ zq2, float* __restrict__ vq_acc) {
    const int b = blockIdx.x;
    const int k = threadIdx.x;
    __shared__ float red[4];
    float best = FLT_MAX; int bi = 0;
    #pragma unroll
    for (int tile = 0; tile < 8; ++tile) {
        const float v = pbest[((size_t)tile * 64 + b) * 256 + k];
        const int   i = pidx [((size_t)tile * 64 + b) * 256 + k];
        if (v < best) { best = v; bi = i; } // tiles ascending -> first-min preserved
    }
    codes[b * 256 + k] = bi;
    const float* __restrict__ cw = cb + (size_t)bi * 64;
    float part = 0.f;
    #pragma unroll
    for (int d = 0; d < 64; ++d) {
        const size_t loc = ((size_t)(b * 64 + d)) * 256 + k;
        const float c = cw[d];
        const float zv = z[loc];             // read before zq2 may overwrite (same thread)
        zq[loc] = c;
        zq2[loc] = fmaf(0.01f, nz[loc], c);
        const float df = c - zv;
        part = fmaf(df, df, part);
    }
    const float tot = blockReduceSum256(part, red);
    if (threadIdx.x == 0) atomicAdd(vq_acc, tot);
}

// ---------------- softmax over length dim ----------------
__global__ __launch_bounds__(256)
void softmax_kernel(const float* __restrict__ yraw, float* __restrict__ y) {
    const int bc = blockIdx.x;
    const float* __restrict__ r = yraw + (size_t)bc * 1024;
    float* __restrict__ o = y + (size_t)bc * 1024;
    __shared__ float buf[4];
    float v[4];
    float mx = -FLT_MAX;
    #pragma unroll
    for (int j = 0; j < 4; ++j) { v[j] = r[threadIdx.x + 256 * j]; mx = fmaxf(mx, v[j]); }
    #pragma unroll
    for (int m = 32; m > 0; m >>= 1) mx = fmaxf(mx, __shfl_xor(mx, m, 64));
    if ((threadIdx.x & 63) == 0) buf[threadIdx.x >> 6] = mx;
    __syncthreads();
    mx = fmaxf(fmaxf(buf[0], buf[1]), fmaxf(buf[2], buf[3]));
    __syncthreads();
    float e[4]; float s = 0.f;
    #pragma unroll
    for (int j = 0; j < 4; ++j) { e[j] = expf(v[j] - mx); s += e[j]; }
    #pragma unroll
    for (int m = 32; m > 0; m >>= 1) s += __shfl_xor(s, m, 64);
    if ((threadIdx.x & 63) == 0) buf[threadIdx.x >> 6] = s;
    __syncthreads();
    s = (buf[0] + buf[1]) + (buf[2] + buf[3]);
    #pragma unroll
    for (int j = 0; j < 4; ++j) o[threadIdx.x + 256 * j] = e[j] / s;
}

// ---------------- lv branch: partials over quarters ----------------
__global__ __launch_bounds__(256)
void lv_kernel(const float* __restrict__ h2, const float* __restrict__ wlv,
               float* __restrict__ lvp) {
    const int b = blockIdx.x, zz = blockIdx.y;
    __shared__ float red[4];
    const float4* __restrict__ hb =
        reinterpret_cast<const float4*>(h2 + (size_t)b * 65536) + (size_t)zz * 4096;
    float s = 0.f;
    for (int i = threadIdx.x; i < 4096; i += 256) {
        const float4 v = hb[i];
        const float wc = wlv[(zz * 4096 + i) >> 8];
        s = fmaf((v.x + v.y) + (v.z + v.w), wc, s);
    }
    const float tot = blockReduceSum256(s, red);
    if (threadIdx.x == 0) lvp[zz * 64 + b] = tot;
}

// ---------------- crv branch ----------------
__global__ __launch_bounds__(256)
void dist_kernel(const float* __restrict__ y, float* __restrict__ dist) {
    const int j = blockIdx.x, i = blockIdx.y;
    if (i > j) return;
    __shared__ float red[4];
    const float4* __restrict__ yi = reinterpret_cast<const float4*>(y + (size_t)i * 8192);
    const float4* __restrict__ yj = reinterpret_cast<const float4*>(y + (size_t)j * 8192);
    float s = 0.f;
    for (int e = threadIdx.x; e < 2048; e += 256) {
        const float4 a = yi[e], c = yj[e];
        const float d0 = a.x - c.x, d1 = a.y - c.y, d2 = a.z - c.z, d3 = a.w - c.w;
        s = fmaf(d0, d0, s); s = fmaf(d1, d1, s);
        s = fmaf(d2, d2, s); s = fmaf(d3, d3, s);
    }
    const float tot = blockReduceSum256(s, red);
    if (threadIdx.x == 0) {
        const float v = tot * (1.f / 8192.f);
        dist[i * 64 + j] = v;
        dist[j * 64 + i] = v;
    }
}

__global__ __launch_bounds__(256)
void crv_kernel(const int* __restrict__ codes, const float* __restrict__ dist,
                float* __restrict__ crv_acc) {
    const int kk = blockIdx.x;
    __shared__ int ck[64];
    __shared__ float red[4];
    if (threadIdx.x < 64) ck[threadIdx.x] = codes[threadIdx.x * 256 + kk];
    __syncthreads();
    float sn = 0.f, sd = 0.f;
    for (int idx = threadIdx.x; idx < 4096; idx += 256) {
        const int i = idx >> 6, j = idx & 63;
        if (ck[i] == ck[j]) { sn += dist[idx]; sd += 1.f; }
    }
    const float tn = blockReduceSum256(sn, red);
    const float td = blockReduceSum256(sd, red);
    if (threadIdx.x == 0) atomicAdd(crv_acc, tn / (td + 1e-6f));
}

// ---------------- finalize: lv_loss grid + scalars ----------------
__global__ __launch_bounds__(256)
void final_kernel(const float* __restrict__ tgt, const float* __restrict__ lvp,
                  const float* __restrict__ blv, const float* __restrict__ acc,
                  float* __restrict__ out) {
    const int idx = blockIdx.x * 256 + threadIdx.x; // 4096
    const int i = idx >> 6, j = idx & 63;
    const float lvj = ((lvp[j] + lvp[64 + j]) + (lvp[128 + j] + lvp[192 + j]))
                      * (1.f / 1024.f) + blv[0];
    const float d = tgt[i] - lvj;
    out[OUT_LV + idx] = d * d;
    if (idx == 0) {
        out[528384] = 0.25f * acc[0] * (1.f / 1048576.f);            // vq_loss
        const float lip = acc[1] * (1.f / 524288.f) * 1e4f;          // /EPS^2
        const float crv = acc[2] * (1.f / 256.f);
        out[528385] = lip + crv;                                     // smoothness
    }
}

// ---------------- launch ----------------
extern "C" void kernel_launch(void* const* d_in, const int* in_sizes, int n_in,
                              void* d_out, int out_size, void* d_ws, size_t ws_size,
                              hipStream_t stream) {
    const float* x   = (const float*)d_in[0];
    const float* We1 = (const float*)d_in[1];
    const float* be1 = (const float*)d_in[2];
    const float* We2 = (const float*)d_in[3];
    const float* be2 = (const float*)d_in[4];
    const float* We3 = (const float*)d_in[5];
    const float* be3 = (const float*)d_in[6];
    const float* Wd1 = (const float*)d_in[7];
    const float* bd1 = (const float*)d_in[8];
    const float* Wd2 = (const float*)d_in[9];
    const float* bd2 = (const float*)d_in[10];
    const float* Wd3 = (const float*)d_in[11];
    const float* bd3 = (const float*)d_in[12];
    const float* cb  = (const float*)d_in[13];
    const float* Wlv = (const float*)d_in[14];
    const float* blv = (const float*)d_in[15];
    const float* nz  = (const float*)d_in[16];
    float* out = (float*)d_out;
    float* ws  = (float*)d_ws;

    float* cnorm = ws + F_CN;
    float* lvp   = ws + F_LVP;
    float* tgt   = ws + F_TGT;
    float* acc   = ws + F_ACC;
    int*   codes = (int*)(ws + F_CODES);
    float* dist  = ws + F_DIST;
    float* pbest = ws + F_PBEST;
    int*   pidx  = (int*)(ws + F_PIDX);

    const bool fused = ws_size >= (size_t)A_END * sizeof(float);

    preamble_kernel<<<67, 256, 0, stream>>>(x, cb, cnorm, tgt, acc);

    if (fused) {
        float* yraw = ws + A_YRAW;
        float* z2   = ws + A_Z2;                 // [128][64][256]: zq | zq2
        float* h1   = ws + A_H1;                 // [128][128][512]
        float* h2   = ws + A_H2;                 // [128][64][1024]
        float* h1e  = h1;                        // enc temps overlap h1
        float* h2e  = h1 + 2097152;
        float* z    = h2;                        // pre-VQ z overlaps h2
        float* zq   = z2;
        float* zq2  = z2 + 1048576;

        // encoder
        conv_s2k4<8, 1024, 512, 8, true><<<dim3(8, 64, 2), 256, 0, stream>>>(x, We1, be1, h1e);
        conv_s2k4<64, 512, 256, 16, true><<<dim3(8, 64, 1), 256, 0, stream>>>(h1e, We2, be2, h2e);
        conv_s1k3<128, 256, 16, false><<<dim3(4, 64, 1), 256, 0, stream>>>(h2e, We3, be3, z);

        // VQ (emits both decoder inputs)
        vq_dist_kernel<<<dim3(8, 64), 256, 0, stream>>>(z, cb, cnorm, pbest, pidx);
        vq_combine_kernel<<<64, 256, 0, stream>>>(z, cb, pbest, pidx, nz, codes, zq, zq2, &acc[0]);

        // fused decoder, batch 128 (both streams)
        convT_tiled<64, 256, 16, true><<<dim3(8, 128, 1), 256, 0, stream>>>(z2, Wd1, bd1, h1);
        convT_tiled<128, 512, 16, true><<<dim3(4, 128, 2), 256, 0, stream>>>(h1, Wd2, bd2, h2);
        lv_kernel<<<dim3(64, 4), 256, 0, stream>>>(h2, Wlv, lvp);  // stream0 rows only
        convd3_both<<<dim3(4, 64), 256, 0, stream>>>(h2, h2 + (size_t)64 * 65536,
                                                     Wd3, bd3, yraw, &acc[1]);
        softmax_kernel<<<512, 256, 0, stream>>>(yraw, out);
    } else {
        float* yraw = ws + B_YRAW;
        float* zq   = ws + B_ZQ;
        float* z    = ws + B_Z;                  // z, then zq2 in-place
        float* h2d  = ws + B_H2;
        float* big  = ws + B_BIG;
        float* h1e  = big;
        float* h2e  = big + 2097152;

        conv_s2k4<8, 1024, 512, 8, true><<<dim3(8, 64, 2), 256, 0, stream>>>(x, We1, be1, h1e);
        conv_s2k4<64, 512, 256, 16, true><<<dim3(8, 64, 1), 256, 0, stream>>>(h1e, We2, be2, h2e);
        conv_s1k3<128, 256, 16, false><<<dim3(4, 64, 1), 256, 0, stream>>>(h2e, We3, be3, z);

        vq_dist_kernel<<<dim3(8, 64), 256, 0, stream>>>(z, cb, cnorm, pbest, pidx);
        vq_combine_kernel<<<64, 256, 0, stream>>>(z, cb, pbest, pidx, nz, codes, zq, z, &acc[0]);

        // pass 1 (clean)
        convT_tiled<64, 256, 16, true><<<dim3(8, 64, 1), 256, 0, stream>>>(zq, Wd1, bd1, big);
        convT_tiled<128, 512, 16, true><<<dim3(4, 64, 2), 256, 0, stream>>>(big, Wd2, bd2, h2d);
        convd3_tiled<false><<<dim3(4, 64), 256, 0, stream>>>(h2d, Wd3, bd3, yraw, nullptr, nullptr);
        softmax_kernel<<<512, 256, 0, stream>>>(yraw, out);
        lv_kernel<<<dim3(64, 4), 256, 0, stream>>>(h2d, Wlv, lvp);

        // pass 2 (perturbed)
        convT_tiled<64, 256, 16, true><<<dim3(8, 64, 1), 256, 0, stream>>>(z, Wd1, bd1, big);
        convT_tiled<128, 512, 16, true><<<dim3(4, 64, 2), 256, 0, stream>>>(big, Wd2, bd2, h2d);
        convd3_tiled<true><<<dim3(4, 64), 256, 0, stream>>>(h2d, Wd3, bd3, nullptr, yraw, &acc[1]);
    }

    // crv branch + outputs
    dist_kernel<<<dim3(64, 64), 256, 0, stream>>>(out, dist);
    crv_kernel<<<256, 256, 0, stream>>>(codes, dist, &acc[2]);
    final_kernel<<<16, 256, 0, stream>>>(tgt, lvp, blv, acc, out);
}

// Round 5
// 456.774 us; speedup vs baseline: 1.0055x; 1.0055x over previous
//
#include <hip/hip_runtime.h>
#include <float.h>
#include <math.h>

#define DEV_INLINE __device__ __forceinline__

// ---------------- problem constants ----------------
// B=64, C_IN=8, L=1024, D=64, K=256, E=512, BETA=0.25, EPS_LIP=0.01

// ---------------- ws layout (float offsets) ----------------
static constexpr size_t F_CN    = 0;       // 512   : |c_e|^2
static constexpr size_t F_LVP   = 512;     // 256   : lv partials [4][B]
static constexpr size_t F_TGT   = 768;     // 64    : log-sum targets
static constexpr size_t F_ACC   = 832;     // 16    : [0]=vq [1]=lip [2]=crv
static constexpr size_t F_CODES = 848;     // 16384 : codes [B][K] (int)
static constexpr size_t F_DIST  = 17232;   // 4096  : dist [B][B]
static constexpr size_t F_PBEST = 21328;   // 131072: per-tile best dist [8][B][K]
static constexpr size_t F_PIDX  = 152400;  // 131072: per-tile best idx (int)

static constexpr size_t B_YRAW = 283472;   // 524288 : y_raw [64][8][1024]
static constexpr size_t B_ZQ   = 807760;   // 1048576: zq
static constexpr size_t B_Z    = 1856336;  // 1048576: z, then zq2 in-place
static constexpr size_t B_H2   = 2904912;  // 4194304: h2 [64][64][1024]
static constexpr size_t B_BIG  = 7099216;  // 4194304: h1e|h2e (enc), then dec h1
// total 11,293,520 floats = ~45.2 MB

// out layout: y [64*8*1024] | lv_loss [64*64] | vq_loss | smoothness
static constexpr size_t OUT_LV = 524288;

// ---------------- reduction helpers ----------------
DEV_INLINE float waveReduceSum(float v) {
    #pragma unroll
    for (int m = 32; m > 0; m >>= 1) v += __shfl_xor(v, m, 64);
    return v;
}

DEV_INLINE float blockReduceSum256(float v, float* buf) {
    __syncthreads();
    v = waveReduceSum(v);
    if ((threadIdx.x & 63) == 0) buf[threadIdx.x >> 6] = v;
    __syncthreads();
    return (buf[0] + buf[1]) + (buf[2] + buf[3]);
}

// ---------------- preamble: acc zero + cnorm + tgt ----------------
__global__ __launch_bounds__(256)
void preamble_kernel(const float* __restrict__ x, const float* __restrict__ cb,
                     float* __restrict__ cnorm, float* __restrict__ tgt,
                     float* __restrict__ acc) {
    const int blk = blockIdx.x;
    if (blk < 64) {
        __shared__ float red[4];
        const float* __restrict__ xb = x + (size_t)blk * 8 * 1024;
        float s = 0.f;
        for (int t = threadIdx.x; t < 1024; t += 256) s += xb[t];
        const float tot = blockReduceSum256(s, red);
        if (threadIdx.x == 0) tgt[blk] = logf(tot + 1e-7f);
    } else if (blk < 66) {
        const int e = (blk - 64) * 256 + threadIdx.x;
        const float* __restrict__ c = cb + (size_t)e * 64;
        float s = 0.f;
        #pragma unroll
        for (int d = 0; d < 64; ++d) s = fmaf(c[d], c[d], s);
        cnorm[e] = s;
    } else {
        if (threadIdx.x < 16) acc[threadIdx.x] = 0.f;
    }
}

// ---------------- conv kernels: SGPR weights, TT=2, no LDS ----------------
// stride-2 k=4 pad=1. 128 thr; thread = t-pair gid. grid (Cout/OG, B, LOUT/256).
// out[t] = sum_i sum_dk w[o][i][dk] * x[i][2t-1+dk]
template<int CIN, int LIN, int LOUT, int OG, bool RELU>
__global__ __launch_bounds__(128)
void conv_s2k4_sg(const float* __restrict__ in, const float* __restrict__ w,
                  const float* __restrict__ bias, float* __restrict__ out) {
    const int og = blockIdx.x;
    const int b  = blockIdx.y;
    const int gid = blockIdx.z * 128 + threadIdx.x;   // 0..LOUT/2-1
    const float* __restrict__ inb = in + (size_t)b * CIN * LIN;
    const float4* __restrict__ wg = reinterpret_cast<const float4*>(w) + (size_t)og * OG * CIN;
    float acc0[OG], acc1[OG];
    #pragma unroll
    for (int oo = 0; oo < OG; ++oo) { acc0[oo] = 0.f; acc1[oo] = 0.f; }
    const bool vm = (gid > 0), vp = (gid < LOUT / 2 - 1);
    const int base = 4 * gid;
    const int qm = vm ? base - 1 : 0, qp = vp ? base + 4 : 0;
    for (int i = 0; i < CIN; ++i) {
        const float* __restrict__ row = inb + (size_t)i * LIN;
        float xm = row[qm]; xm = vm ? xm : 0.f;
        const float x0 = row[base], x1 = row[base + 1];
        const float x2 = row[base + 2], x3 = row[base + 3];
        float xp = row[qp]; xp = vp ? xp : 0.f;
        #pragma unroll
        for (int oo = 0; oo < OG; ++oo) {
            const float4 wv = wg[oo * CIN + i];   // uniform -> s_load_dwordx4
            acc0[oo] = fmaf(xm, wv.x, acc0[oo]);  // t0 = 2*gid
            acc0[oo] = fmaf(x0, wv.y, acc0[oo]);
            acc0[oo] = fmaf(x1, wv.z, acc0[oo]);
            acc0[oo] = fmaf(x2, wv.w, acc0[oo]);
            acc1[oo] = fmaf(x1, wv.x, acc1[oo]);  // t1 = 2*gid+1
            acc1[oo] = fmaf(x2, wv.y, acc1[oo]);
            acc1[oo] = fmaf(x3, wv.z, acc1[oo]);
            acc1[oo] = fmaf(xp, wv.w, acc1[oo]);
        }
    }
    const int Cout = gridDim.x * OG;
    #pragma unroll
    for (int oo = 0; oo < OG; ++oo) {
        const float bb = bias[og * OG + oo];
        float v0 = acc0[oo] + bb, v1 = acc1[oo] + bb;
        if (RELU) { v0 = fmaxf(v0, 0.f); v1 = fmaxf(v1, 0.f); }
        reinterpret_cast<float2*>(out + ((size_t)b * Cout + og * OG + oo) * LOUT)[gid] =
            make_float2(v0, v1);
    }
}

// stride-1 k=3 pad=1. 128 thr; thread = t-pair gid. grid (Cout/OG, B, LIN/256).
template<int CIN, int LIN, int OG, bool RELU>
__global__ __launch_bounds__(128)
void conv_s1k3_sg(const float* __restrict__ in, const float* __restrict__ w,
                  const float* __restrict__ bias, float* __restrict__ out) {
    const int og = blockIdx.x;
    const int b  = blockIdx.y;
    const int gid = blockIdx.z * 128 + threadIdx.x;   // 0..LIN/2-1
    const float* __restrict__ inb = in + (size_t)b * CIN * LIN;
    float acc0[OG], acc1[OG];
    #pragma unroll
    for (int oo = 0; oo < OG; ++oo) { acc0[oo] = 0.f; acc1[oo] = 0.f; }
    const bool vm = (gid > 0), vp = (gid < LIN / 2 - 1);
    const int t0 = 2 * gid;
    const int qm = vm ? t0 - 1 : 0, qp = vp ? t0 + 2 : 0;
    for (int i = 0; i < CIN; ++i) {
        const float* __restrict__ row = inb + (size_t)i * LIN;
        float xm = row[qm]; xm = vm ? xm : 0.f;
        const float x0 = row[t0], x1 = row[t0 + 1];
        float xp = row[qp]; xp = vp ? xp : 0.f;
        #pragma unroll
        for (int oo = 0; oo < OG; ++oo) {
            const float* __restrict__ wr = w + ((size_t)(og * OG + oo) * CIN + i) * 3;
            const float w0 = wr[0], w1 = wr[1], w2 = wr[2];  // uniform -> s_load
            acc0[oo] = fmaf(xm, w0, acc0[oo]);
            acc0[oo] = fmaf(x0, w1, acc0[oo]);
            acc0[oo] = fmaf(x1, w2, acc0[oo]);
            acc1[oo] = fmaf(x0, w0, acc1[oo]);
            acc1[oo] = fmaf(x1, w1, acc1[oo]);
            acc1[oo] = fmaf(xp, w2, acc1[oo]);
        }
    }
    const int Cout = gridDim.x * OG;
    #pragma unroll
    for (int oo = 0; oo < OG; ++oo) {
        const float bb = bias[og * OG + oo];
        float v0 = acc0[oo] + bb, v1 = acc1[oo] + bb;
        if (RELU) { v0 = fmaxf(v0, 0.f); v1 = fmaxf(v1, 0.f); }
        reinterpret_cast<float2*>(out + ((size_t)b * Cout + og * OG + oo) * LIN)[gid] =
            make_float2(v0, v1);
    }
}

// ConvTranspose1d (k=4,s=2,p=1) gather. 128 thr; thread = te-pair gid; 4 outputs.
// grid (Cout/OG, B, LIN/256).
// t=2te:   x[te-1]*w0 + x[te]*w2 ; t=2te+1: x[te]*w1 + x[te+1]*w3
template<int CIN, int LIN, int OG, bool RELU>
__global__ __launch_bounds__(128)
void convT_sg(const float* __restrict__ in, const float* __restrict__ w,
              const float* __restrict__ bias, float* __restrict__ out) {
    const int og = blockIdx.x;
    const int b  = blockIdx.y;
    const int gid = blockIdx.z * 128 + threadIdx.x;   // 0..LIN/2-1
    const int te0 = 2 * gid;
    const float* __restrict__ inb = in + (size_t)b * CIN * LIN;
    const float4* __restrict__ wg = reinterpret_cast<const float4*>(w) + (size_t)og * OG * CIN;
    float a0[OG], a1[OG], a2[OG], a3[OG];
    #pragma unroll
    for (int oo = 0; oo < OG; ++oo) { a0[oo] = 0.f; a1[oo] = 0.f; a2[oo] = 0.f; a3[oo] = 0.f; }
    const bool vm = (gid > 0), vp = (gid < LIN / 2 - 1);
    const int qm = vm ? te0 - 1 : 0, qp = vp ? te0 + 2 : 0;
    for (int i = 0; i < CIN; ++i) {
        const float* __restrict__ row = inb + (size_t)i * LIN;
        float xm = row[qm]; xm = vm ? xm : 0.f;
        const float x0 = row[te0], x1 = row[te0 + 1];
        float xp = row[qp]; xp = vp ? xp : 0.f;
        #pragma unroll
        for (int oo = 0; oo < OG; ++oo) {
            const float4 wv = wg[oo * CIN + i];   // uniform -> s_load_dwordx4
            a0[oo] = fmaf(xm, wv.x, a0[oo]);      // t=2*te0
            a0[oo] = fmaf(x0, wv.z, a0[oo]);
            a1[oo] = fmaf(x0, wv.y, a1[oo]);      // t=2*te0+1
            a1[oo] = fmaf(x1, wv.w, a1[oo]);
            a2[oo] = fmaf(x0, wv.x, a2[oo]);      // t=2*te0+2
            a2[oo] = fmaf(x1, wv.z, a2[oo]);
            a3[oo] = fmaf(x1, wv.y, a3[oo]);      // t=2*te0+3
            a3[oo] = fmaf(xp, wv.w, a3[oo]);
        }
    }
    const int Cout = gridDim.x * OG;
    #pragma unroll
    for (int oo = 0; oo < OG; ++oo) {
        const float bb = bias[og * OG + oo];
        float v0 = a0[oo] + bb, v1 = a1[oo] + bb, v2 = a2[oo] + bb, v3 = a3[oo] + bb;
        if (RELU) {
            v0 = fmaxf(v0, 0.f); v1 = fmaxf(v1, 0.f);
            v2 = fmaxf(v2, 0.f); v3 = fmaxf(v3, 0.f);
        }
        reinterpret_cast<float4*>(out + ((size_t)b * Cout + og * OG + oo) * (2 * LIN))[gid] =
            make_float4(v0, v1, v2, v3);
    }
}

// final conv (64->8, k=3, s=1, p=1), all 8 out channels, SGPR weights.
// grid (4, B), 256 thr. LIP=true: accumulate (y2 - yref)^2 instead of storing.
template<bool LIP>
__global__ __launch_bounds__(256)
void convd3_sg(const float* __restrict__ in, const float* __restrict__ w,
               const float* __restrict__ bias, float* __restrict__ yraw_out,
               const float* __restrict__ yraw_ref, float* __restrict__ lip_acc) {
    const int b = blockIdx.y;
    const int t = blockIdx.x * 256 + threadIdx.x;
    __shared__ float red[4];
    const float* __restrict__ inb = in + (size_t)b * 65536;
    float acc[8];
    #pragma unroll
    for (int oo = 0; oo < 8; ++oo) acc[oo] = 0.f;
    const bool vl = (t > 0), vr = (t < 1023);
    const int ql = vl ? t - 1 : 0, qr = vr ? t + 1 : 0;
    for (int i = 0; i < 64; ++i) {
        const float* __restrict__ row = inb + (size_t)i * 1024;
        float x0 = row[ql]; x0 = vl ? x0 : 0.f;
        const float x1 = row[t];
        float x2 = row[qr]; x2 = vr ? x2 : 0.f;
        #pragma unroll
        for (int oo = 0; oo < 8; ++oo) {
            const float* __restrict__ wr = w + ((size_t)oo * 64 + i) * 3;
            acc[oo] = fmaf(x0, wr[0], acc[oo]);
            acc[oo] = fmaf(x1, wr[1], acc[oo]);
            acc[oo] = fmaf(x2, wr[2], acc[oo]);
        }
    }
    const size_t obase = (size_t)b * 8192 + t;
    if (!LIP) {
        #pragma unroll
        for (int oo = 0; oo < 8; ++oo)
            yraw_out[obase + (size_t)oo * 1024] = acc[oo] + bias[oo];
    } else {
        float lpart = 0.f;
        #pragma unroll
        for (int oo = 0; oo < 8; ++oo) {
            const float d = (acc[oo] + bias[oo]) - yraw_ref[obase + (size_t)oo * 1024];
            lpart = fmaf(d, d, lpart);
        }
        const float tot = blockReduceSum256(lpart, red);
        if (threadIdx.x == 0) atomicAdd(lip_acc, tot);
    }
}

// ---------------- VQ ----------------
// grid (8 code-tiles, B). thread = k. z[b,:,k] in regs; codebook via uniform s_loads.
__global__ __launch_bounds__(256)
void vq_dist_kernel(const float* __restrict__ z, const float* __restrict__ cb,
                    const float* __restrict__ cnorm,
                    float* __restrict__ pbest, int* __restrict__ pidx) {
    const int tile = blockIdx.x;
    const int b = blockIdx.y;
    const int k = threadIdx.x;
    float zr[64];
    #pragma unroll
    for (int d = 0; d < 64; ++d) zr[d] = z[((size_t)(b * 64 + d)) * 256 + k];
    const float4* __restrict__ cb4 =
        reinterpret_cast<const float4*>(cb) + (size_t)tile * 64 * 16;
    float best = FLT_MAX; int bi = 0;
    for (int e = 0; e < 64; ++e) {
        float d0 = 0.f, d1 = 0.f, d2 = 0.f, d3 = 0.f;
        #pragma unroll
        for (int q = 0; q < 16; ++q) {
            const float4 c4 = cb4[e * 16 + q];    // uniform -> s_load_dwordx4
            d0 = fmaf(zr[4 * q + 0], c4.x, d0);
            d1 = fmaf(zr[4 * q + 1], c4.y, d1);
            d2 = fmaf(zr[4 * q + 2], c4.z, d2);
            d3 = fmaf(zr[4 * q + 3], c4.w, d3);
        }
        const float dist = cnorm[tile * 64 + e] - 2.f * ((d0 + d1) + (d2 + d3));
        if (dist < best) { best = dist; bi = tile * 64 + e; }  // strict < : first-min
    }
    pbest[((size_t)tile * 64 + b) * 256 + k] = best;
    pidx [((size_t)tile * 64 + b) * 256 + k] = bi;
}

// combine tiles; grid (B, 4): each block handles 16 d's. chunk 0 writes codes.
__global__ __launch_bounds__(256)
void vq_combine_kernel(const float* __restrict__ z, const float* __restrict__ cb,
                       const float* __restrict__ pbest, const int* __restrict__ pidx,
                       const float* __restrict__ nz,
                       int* __restrict__ codes, float* __restrict__ zq,
                       float* __restrict__ zq2, float* __restrict__ vq_acc) {
    const int b = blockIdx.x;
    const int dc = blockIdx.y * 16;
    const int k = threadIdx.x;
    __shared__ float red[4];
    float best = FLT_MAX; int bi = 0;
    #pragma unroll
    for (int tile = 0; tile < 8; ++tile) {
        const float v = pbest[((size_t)tile * 64 + b) * 256 + k];
        const int   i = pidx [((size_t)tile * 64 + b) * 256 + k];
        if (v < best) { best = v; bi = i; }  // ascending tiles -> first-min
    }
    if (blockIdx.y == 0) codes[b * 256 + k] = bi;
    const float* __restrict__ cw = cb + (size_t)bi * 64;
    float part = 0.f;
    #pragma unroll
    for (int dd = 0; dd < 16; ++dd) {
        const int d = dc + dd;
        const size_t loc = ((size_t)(b * 64 + d)) * 256 + k;
        const float c = cw[d];                 // divergent gather
        const float zv = z[loc];               // read before aliased zq2 write
        zq[loc] = c;
        zq2[loc] = fmaf(0.01f, nz[loc], c);
        const float df = c - zv;
        part = fmaf(df, df, part);
    }
    const float tot = blockReduceSum256(part, red);
    if (threadIdx.x == 0) atomicAdd(vq_acc, tot);
}

// ---------------- softmax over length dim ----------------
__global__ __launch_bounds__(256)
void softmax_kernel(const float* __restrict__ yraw, float* __restrict__ y) {
    const int bc = blockIdx.x;
    const float* __restrict__ r = yraw + (size_t)bc * 1024;
    float* __restrict__ o = y + (size_t)bc * 1024;
    __shared__ float buf[4];
    float v[4];
    float mx = -FLT_MAX;
    #pragma unroll
    for (int j = 0; j < 4; ++j) { v[j] = r[threadIdx.x + 256 * j]; mx = fmaxf(mx, v[j]); }
    #pragma unroll
    for (int m = 32; m > 0; m >>= 1) mx = fmaxf(mx, __shfl_xor(mx, m, 64));
    if ((threadIdx.x & 63) == 0) buf[threadIdx.x >> 6] = mx;
    __syncthreads();
    mx = fmaxf(fmaxf(buf[0], buf[1]), fmaxf(buf[2], buf[3]));
    __syncthreads();
    float e[4]; float s = 0.f;
    #pragma unroll
    for (int j = 0; j < 4; ++j) { e[j] = expf(v[j] - mx); s += e[j]; }
    #pragma unroll
    for (int m = 32; m > 0; m >>= 1) s += __shfl_xor(s, m, 64);
    if ((threadIdx.x & 63) == 0) buf[threadIdx.x >> 6] = s;
    __syncthreads();
    s = (buf[0] + buf[1]) + (buf[2] + buf[3]);
    #pragma unroll
    for (int j = 0; j < 4; ++j) o[threadIdx.x + 256 * j] = e[j] / s;
}

// ---------------- lv branch: partials over quarters ----------------
__global__ __launch_bounds__(256)
void lv_kernel(const float* __restrict__ h2, const float* __restrict__ wlv,
               float* __restrict__ lvp) {
    const int b = blockIdx.x, zz = blockIdx.y;
    __shared__ float red[4];
    const float4* __restrict__ hb =
        reinterpret_cast<const float4*>(h2 + (size_t)b * 65536) + (size_t)zz * 4096;
    float s = 0.f;
    for (int i = threadIdx.x; i < 4096; i += 256) {
        const float4 v = hb[i];
        const float wc = wlv[(zz * 4096 + i) >> 8];   // uniform per iteration
        s = fmaf((v.x + v.y) + (v.z + v.w), wc, s);
    }
    const float tot = blockReduceSum256(s, red);
    if (threadIdx.x == 0) lvp[zz * 64 + b] = tot;
}

// ---------------- crv branch ----------------
__global__ __launch_bounds__(256)
void dist_kernel(const float* __restrict__ y, float* __restrict__ dist) {
    const int j = blockIdx.x, i = blockIdx.y;
    if (i > j) return;
    __shared__ float red[4];
    const float4* __restrict__ yi = reinterpret_cast<const float4*>(y + (size_t)i * 8192);
    const float4* __restrict__ yj = reinterpret_cast<const float4*>(y + (size_t)j * 8192);
    float s = 0.f;
    for (int e = threadIdx.x; e < 2048; e += 256) {
        const float4 a = yi[e], c = yj[e];
        const float d0 = a.x - c.x, d1 = a.y - c.y, d2 = a.z - c.z, d3 = a.w - c.w;
        s = fmaf(d0, d0, s); s = fmaf(d1, d1, s);
        s = fmaf(d2, d2, s); s = fmaf(d3, d3, s);
    }
    const float tot = blockReduceSum256(s, red);
    if (threadIdx.x == 0) {
        const float v = tot * (1.f / 8192.f);
        dist[i * 64 + j] = v;
        dist[j * 64 + i] = v;
    }
}

__global__ __launch_bounds__(256)
void crv_kernel(const int* __restrict__ codes, const float* __restrict__ dist,
                float* __restrict__ crv_acc) {
    const int kk = blockIdx.x;
    __shared__ int ck[64];
    __shared__ float red[4];
    if (threadIdx.x < 64) ck[threadIdx.x] = codes[threadIdx.x * 256 + kk];
    __syncthreads();
    float sn = 0.f, sd = 0.f;
    for (int idx = threadIdx.x; idx < 4096; idx += 256) {
        const int i = idx >> 6, j = idx & 63;
        if (ck[i] == ck[j]) { sn += dist[idx]; sd += 1.f; }
    }
    const float tn = blockReduceSum256(sn, red);
    const float td = blockReduceSum256(sd, red);
    if (threadIdx.x == 0) atomicAdd(crv_acc, tn / (td + 1e-6f));
}

// ---------------- finalize: lv_loss grid + scalars ----------------
__global__ __launch_bounds__(256)
void final_kernel(const float* __restrict__ tgt, const float* __restrict__ lvp,
                  const float* __restrict__ blv, const float* __restrict__ acc,
                  float* __restrict__ out) {
    const int idx = blockIdx.x * 256 + threadIdx.x; // 4096
    const int i = idx >> 6, j = idx & 63;
    const float lvj = ((lvp[j] + lvp[64 + j]) + (lvp[128 + j] + lvp[192 + j]))
                      * (1.f / 1024.f) + blv[0];
    const float d = tgt[i] - lvj;
    out[OUT_LV + idx] = d * d;
    if (idx == 0) {
        out[528384] = 0.25f * acc[0] * (1.f / 1048576.f);            // vq_loss
        const float lip = acc[1] * (1.f / 524288.f) * 1e4f;          // /EPS^2
        const float crv = acc[2] * (1.f / 256.f);
        out[528385] = lip + crv;                                     // smoothness
    }
}

// ---------------- launch ----------------
extern "C" void kernel_launch(void* const* d_in, const int* in_sizes, int n_in,
                              void* d_out, int out_size, void* d_ws, size_t ws_size,
                              hipStream_t stream) {
    const float* x   = (const float*)d_in[0];
    const float* We1 = (const float*)d_in[1];
    const float* be1 = (const float*)d_in[2];
    const float* We2 = (const float*)d_in[3];
    const float* be2 = (const float*)d_in[4];
    const float* We3 = (const float*)d_in[5];
    const float* be3 = (const float*)d_in[6];
    const float* Wd1 = (const float*)d_in[7];
    const float* bd1 = (const float*)d_in[8];
    const float* Wd2 = (const float*)d_in[9];
    const float* bd2 = (const float*)d_in[10];
    const float* Wd3 = (const float*)d_in[11];
    const float* bd3 = (const float*)d_in[12];
    const float* cb  = (const float*)d_in[13];
    const float* Wlv = (const float*)d_in[14];
    const float* blv = (const float*)d_in[15];
    const float* nz  = (const float*)d_in[16];
    float* out = (float*)d_out;
    float* ws  = (float*)d_ws;

    float* cnorm = ws + F_CN;
    float* lvp   = ws + F_LVP;
    float* tgt   = ws + F_TGT;
    float* acc   = ws + F_ACC;
    int*   codes = (int*)(ws + F_CODES);
    float* dist  = ws + F_DIST;
    float* pbest = ws + F_PBEST;
    int*   pidx  = (int*)(ws + F_PIDX);

    float* yraw = ws + B_YRAW;
    float* zq   = ws + B_ZQ;
    float* z    = ws + B_Z;                  // z, then zq2 in-place
    float* h2d  = ws + B_H2;
    float* big  = ws + B_BIG;
    float* h1e  = big;
    float* h2e  = big + 2097152;

    preamble_kernel<<<67, 256, 0, stream>>>(x, cb, cnorm, tgt, acc);

    // encoder
    conv_s2k4_sg<8, 1024, 512, 8, true><<<dim3(8, 64, 2), 128, 0, stream>>>(x, We1, be1, h1e);
    conv_s2k4_sg<64, 512, 256, 8, true><<<dim3(16, 64, 1), 128, 0, stream>>>(h1e, We2, be2, h2e);
    conv_s1k3_sg<128, 256, 8, false><<<dim3(8, 64, 1), 128, 0, stream>>>(h2e, We3, be3, z);

    // VQ (emits zq and zq2 = zq + 0.01*noise; zq2 overwrites z in-place)
    vq_dist_kernel<<<dim3(8, 64), 256, 0, stream>>>(z, cb, cnorm, pbest, pidx);
    vq_combine_kernel<<<dim3(64, 4), 256, 0, stream>>>(z, cb, pbest, pidx, nz,
                                                       codes, zq, z, &acc[0]);

    // decoder pass 1 (clean)
    convT_sg<64, 256, 8, true><<<dim3(16, 64, 1), 128, 0, stream>>>(zq, Wd1, bd1, big);
    convT_sg<128, 512, 8, true><<<dim3(8, 64, 2), 128, 0, stream>>>(big, Wd2, bd2, h2d);
    convd3_sg<false><<<dim3(4, 64), 256, 0, stream>>>(h2d, Wd3, bd3, yraw, nullptr, nullptr);
    softmax_kernel<<<512, 256, 0, stream>>>(yraw, out);
    lv_kernel<<<dim3(64, 4), 256, 0, stream>>>(h2d, Wlv, lvp);

    // decoder pass 2 (perturbed)
    convT_sg<64, 256, 8, true><<<dim3(16, 64, 1), 128, 0, stream>>>(z, Wd1, bd1, big);
    convT_sg<128, 512, 8, true><<<dim3(8, 64, 2), 128, 0, stream>>>(big, Wd2, bd2, h2d);
    convd3_sg<true><<<dim3(4, 64), 256, 0, stream>>>(h2d, Wd3, bd3, nullptr, yraw, &acc[1]);

    // crv branch + outputs
    dist_kernel<<<dim3(64, 64), 256, 0, stream>>>(out, dist);
    crv_kernel<<<256, 256, 0, stream>>>(codes, dist, &acc[2]);
    final_kernel<<<16, 256, 0, stream>>>(tgt, lvp, blv, acc, out);
}

// Round 6
// 428.311 us; speedup vs baseline: 1.0724x; 1.0665x over previous
//
#include <hip/hip_runtime.h>
#include <float.h>
#include <math.h>

#define DEV_INLINE __device__ __forceinline__

// ---------------- problem constants ----------------
// B=64, C_IN=8, L=1024, D=64, K=256, E=512, BETA=0.25, EPS_LIP=0.01

// ---------------- ws layout (float offsets) ----------------
static constexpr size_t F_CN    = 0;       // 512   : |c_e|^2
static constexpr size_t F_LVP   = 512;     // 256   : lv partials [4][B]
static constexpr size_t F_TGT   = 768;     // 64    : log-sum targets
static constexpr size_t F_ACC   = 832;     // 16    : [0]=vq [1]=lip [2]=crv
static constexpr size_t F_CODES = 848;     // 16384 : codes [B][K] (int)
static constexpr size_t F_DIST  = 17232;   // 4096  : dist [B][B]
static constexpr size_t F_PBEST = 21328;   // 131072: per-tile best dist [8][B][K]
static constexpr size_t F_PIDX  = 152400;  // 131072: per-tile best idx (int)

static constexpr size_t B_YRAW = 283472;   // 524288 : y_raw [64][8][1024]
static constexpr size_t B_ZQ   = 807760;   // 1048576: zq
static constexpr size_t B_Z    = 1856336;  // 1048576: z, then zq2 in-place
static constexpr size_t B_H2   = 2904912;  // 4194304: h2 [64][64][1024]
static constexpr size_t B_BIG  = 7099216;  // 4194304: h1e|h2e (enc), then dec h1
// total 11,293,520 floats = ~45.2 MB

// out layout: y [64*8*1024] | lv_loss [64*64] | vq_loss | smoothness
static constexpr size_t OUT_LV = 524288;

// ---------------- reduction helpers ----------------
DEV_INLINE float waveReduceSum(float v) {
    #pragma unroll
    for (int m = 32; m > 0; m >>= 1) v += __shfl_xor(v, m, 64);
    return v;
}

DEV_INLINE float blockReduceSum256(float v, float* buf) {
    __syncthreads();
    v = waveReduceSum(v);
    if ((threadIdx.x & 63) == 0) buf[threadIdx.x >> 6] = v;
    __syncthreads();
    return (buf[0] + buf[1]) + (buf[2] + buf[3]);
}

// ---------------- preamble: acc zero + cnorm + tgt ----------------
__global__ __launch_bounds__(256)
void preamble_kernel(const float* __restrict__ x, const float* __restrict__ cb,
                     float* __restrict__ cnorm, float* __restrict__ tgt,
                     float* __restrict__ acc) {
    const int blk = blockIdx.x;
    if (blk < 64) {
        __shared__ float red[4];
        const float* __restrict__ xb = x + (size_t)blk * 8 * 1024;
        float s = 0.f;
        for (int t = threadIdx.x; t < 1024; t += 256) s += xb[t];
        const float tot = blockReduceSum256(s, red);
        if (threadIdx.x == 0) tgt[blk] = logf(tot + 1e-7f);
    } else if (blk < 66) {
        const int e = (blk - 64) * 256 + threadIdx.x;
        const float* __restrict__ c = cb + (size_t)e * 64;
        float s = 0.f;
        #pragma unroll
        for (int d = 0; d < 64; ++d) s = fmaf(c[d], c[d], s);
        cnorm[e] = s;
    } else {
        if (threadIdx.x < 16) acc[threadIdx.x] = 0.f;
    }
}

// ---------------- conv kernels: SGPR weights, no LDS ----------------
// XCD note: blockIdx.x = b everywhere, so linear_id % 8 == b % 8 -> all blocks
// sharing batch b's input colocate on one XCD and hit its private L2.

// stride-2 k=4 pad=1. 128 thr; thread = t-pair gid. grid (B, Cout/OG, LOUT/256).
// out[t] = sum_i sum_dk w[o][i][dk] * x[i][2t-1+dk]
template<int CIN, int LIN, int LOUT, int OG, int UNR, bool RELU>
__global__ __launch_bounds__(128)
void conv_s2k4_sg(const float* __restrict__ in, const float* __restrict__ w,
                  const float* __restrict__ bias, float* __restrict__ out) {
    const int b  = blockIdx.x;
    const int og = blockIdx.y;
    const int gid = blockIdx.z * 128 + threadIdx.x;   // 0..LOUT/2-1
    const float* __restrict__ inb = in + (size_t)b * CIN * LIN;
    const float4* __restrict__ wg = reinterpret_cast<const float4*>(w) + (size_t)og * OG * CIN;
    float acc0[OG], acc1[OG];
    #pragma unroll
    for (int oo = 0; oo < OG; ++oo) { acc0[oo] = 0.f; acc1[oo] = 0.f; }
    const bool vm = (gid > 0), vp = (gid < LOUT / 2 - 1);
    const int base = 4 * gid;
    const int qm = vm ? base - 1 : 0, qp = vp ? base + 4 : 0;
    #pragma unroll UNR
    for (int i = 0; i < CIN; ++i) {
        const float* __restrict__ row = inb + (size_t)i * LIN;
        float xm = row[qm]; xm = vm ? xm : 0.f;
        const float x0 = row[base], x1 = row[base + 1];
        const float x2 = row[base + 2], x3 = row[base + 3];
        float xp = row[qp]; xp = vp ? xp : 0.f;
        #pragma unroll
        for (int oo = 0; oo < OG; ++oo) {
            const float4 wv = wg[oo * CIN + i];   // uniform -> s_load_dwordx4
            acc0[oo] = fmaf(xm, wv.x, acc0[oo]);  // t0 = 2*gid
            acc0[oo] = fmaf(x0, wv.y, acc0[oo]);
            acc0[oo] = fmaf(x1, wv.z, acc0[oo]);
            acc0[oo] = fmaf(x2, wv.w, acc0[oo]);
            acc1[oo] = fmaf(x1, wv.x, acc1[oo]);  // t1 = 2*gid+1
            acc1[oo] = fmaf(x2, wv.y, acc1[oo]);
            acc1[oo] = fmaf(x3, wv.z, acc1[oo]);
            acc1[oo] = fmaf(xp, wv.w, acc1[oo]);
        }
    }
    const int Cout = gridDim.y * OG;
    #pragma unroll
    for (int oo = 0; oo < OG; ++oo) {
        const float bb = bias[og * OG + oo];
        float v0 = acc0[oo] + bb, v1 = acc1[oo] + bb;
        if (RELU) { v0 = fmaxf(v0, 0.f); v1 = fmaxf(v1, 0.f); }
        reinterpret_cast<float2*>(out + ((size_t)b * Cout + og * OG + oo) * LOUT)[gid] =
            make_float2(v0, v1);
    }
}

// stride-1 k=3 pad=1. 128 thr; thread = t-pair gid. grid (B, Cout/OG, LIN/256).
template<int CIN, int LIN, int OG, int UNR, bool RELU>
__global__ __launch_bounds__(128)
void conv_s1k3_sg(const float* __restrict__ in, const float* __restrict__ w,
                  const float* __restrict__ bias, float* __restrict__ out) {
    const int b  = blockIdx.x;
    const int og = blockIdx.y;
    const int gid = blockIdx.z * 128 + threadIdx.x;   // 0..LIN/2-1
    const float* __restrict__ inb = in + (size_t)b * CIN * LIN;
    float acc0[OG], acc1[OG];
    #pragma unroll
    for (int oo = 0; oo < OG; ++oo) { acc0[oo] = 0.f; acc1[oo] = 0.f; }
    const bool vm = (gid > 0), vp = (gid < LIN / 2 - 1);
    const int t0 = 2 * gid;
    const int qm = vm ? t0 - 1 : 0, qp = vp ? t0 + 2 : 0;
    #pragma unroll UNR
    for (int i = 0; i < CIN; ++i) {
        const float* __restrict__ row = inb + (size_t)i * LIN;
        float xm = row[qm]; xm = vm ? xm : 0.f;
        const float x0 = row[t0], x1 = row[t0 + 1];
        float xp = row[qp]; xp = vp ? xp : 0.f;
        #pragma unroll
        for (int oo = 0; oo < OG; ++oo) {
            const float* __restrict__ wr = w + ((size_t)(og * OG + oo) * CIN + i) * 3;
            const float w0 = wr[0], w1 = wr[1], w2 = wr[2];  // uniform -> s_load
            acc0[oo] = fmaf(xm, w0, acc0[oo]);
            acc0[oo] = fmaf(x0, w1, acc0[oo]);
            acc0[oo] = fmaf(x1, w2, acc0[oo]);
            acc1[oo] = fmaf(x0, w0, acc1[oo]);
            acc1[oo] = fmaf(x1, w1, acc1[oo]);
            acc1[oo] = fmaf(xp, w2, acc1[oo]);
        }
    }
    const int Cout = gridDim.y * OG;
    #pragma unroll
    for (int oo = 0; oo < OG; ++oo) {
        const float bb = bias[og * OG + oo];
        float v0 = acc0[oo] + bb, v1 = acc1[oo] + bb;
        if (RELU) { v0 = fmaxf(v0, 0.f); v1 = fmaxf(v1, 0.f); }
        reinterpret_cast<float2*>(out + ((size_t)b * Cout + og * OG + oo) * LIN)[gid] =
            make_float2(v0, v1);
    }
}

// ConvTranspose1d (k=4,s=2,p=1) gather. 128 thr; thread = te-pair gid; 4 outputs.
// grid (B, Cout/OG, LIN/256).
// t=2te:   x[te-1]*w0 + x[te]*w2 ; t=2te+1: x[te]*w1 + x[te+1]*w3
template<int CIN, int LIN, int OG, int UNR, bool RELU>
__global__ __launch_bounds__(128)
void convT_sg(const float* __restrict__ in, const float* __restrict__ w,
              const float* __restrict__ bias, float* __restrict__ out) {
    const int b  = blockIdx.x;
    const int og = blockIdx.y;
    const int gid = blockIdx.z * 128 + threadIdx.x;   // 0..LIN/2-1
    const int te0 = 2 * gid;
    const float* __restrict__ inb = in + (size_t)b * CIN * LIN;
    const float4* __restrict__ wg = reinterpret_cast<const float4*>(w) + (size_t)og * OG * CIN;
    float a0[OG], a1[OG], a2[OG], a3[OG];
    #pragma unroll
    for (int oo = 0; oo < OG; ++oo) { a0[oo] = 0.f; a1[oo] = 0.f; a2[oo] = 0.f; a3[oo] = 0.f; }
    const bool vm = (gid > 0), vp = (gid < LIN / 2 - 1);
    const int qm = vm ? te0 - 1 : 0, qp = vp ? te0 + 2 : 0;
    #pragma unroll UNR
    for (int i = 0; i < CIN; ++i) {
        const float* __restrict__ row = inb + (size_t)i * LIN;
        float xm = row[qm]; xm = vm ? xm : 0.f;
        const float x0 = row[te0], x1 = row[te0 + 1];
        float xp = row[qp]; xp = vp ? xp : 0.f;
        #pragma unroll
        for (int oo = 0; oo < OG; ++oo) {
            const float4 wv = wg[oo * CIN + i];   // uniform -> s_load_dwordx4
            a0[oo] = fmaf(xm, wv.x, a0[oo]);      // t=2*te0
            a0[oo] = fmaf(x0, wv.z, a0[oo]);
            a1[oo] = fmaf(x0, wv.y, a1[oo]);      // t=2*te0+1
            a1[oo] = fmaf(x1, wv.w, a1[oo]);
            a2[oo] = fmaf(x0, wv.x, a2[oo]);      // t=2*te0+2
            a2[oo] = fmaf(x1, wv.z, a2[oo]);
            a3[oo] = fmaf(x1, wv.y, a3[oo]);      // t=2*te0+3
            a3[oo] = fmaf(xp, wv.w, a3[oo]);
        }
    }
    const int Cout = gridDim.y * OG;
    #pragma unroll
    for (int oo = 0; oo < OG; ++oo) {
        const float bb = bias[og * OG + oo];
        float v0 = a0[oo] + bb, v1 = a1[oo] + bb, v2 = a2[oo] + bb, v3 = a3[oo] + bb;
        if (RELU) {
            v0 = fmaxf(v0, 0.f); v1 = fmaxf(v1, 0.f);
            v2 = fmaxf(v2, 0.f); v3 = fmaxf(v3, 0.f);
        }
        reinterpret_cast<float4*>(out + ((size_t)b * Cout + og * OG + oo) * (2 * LIN))[gid] =
            make_float4(v0, v1, v2, v3);
    }
}

// final conv (64->8, k=3, s=1, p=1), all 8 out channels, SGPR weights.
// grid (B, 4), 256 thr. LIP=true: accumulate (y2 - yref)^2 instead of storing.
template<bool LIP>
__global__ __launch_bounds__(256)
void convd3_sg(const float* __restrict__ in, const float* __restrict__ w,
               const float* __restrict__ bias, float* __restrict__ yraw_out,
               const float* __restrict__ yraw_ref, float* __restrict__ lip_acc) {
    const int b = blockIdx.x;
    const int t = blockIdx.y * 256 + threadIdx.x;
    __shared__ float red[4];
    const float* __restrict__ inb = in + (size_t)b * 65536;
    float acc[8];
    #pragma unroll
    for (int oo = 0; oo < 8; ++oo) acc[oo] = 0.f;
    const bool vl = (t > 0), vr = (t < 1023);
    const int ql = vl ? t - 1 : 0, qr = vr ? t + 1 : 0;
    #pragma unroll 2
    for (int i = 0; i < 64; ++i) {
        const float* __restrict__ row = inb + (size_t)i * 1024;
        float x0 = row[ql]; x0 = vl ? x0 : 0.f;
        const float x1 = row[t];
        float x2 = row[qr]; x2 = vr ? x2 : 0.f;
        #pragma unroll
        for (int oo = 0; oo < 8; ++oo) {
            const float* __restrict__ wr = w + ((size_t)oo * 64 + i) * 3;
            acc[oo] = fmaf(x0, wr[0], acc[oo]);
            acc[oo] = fmaf(x1, wr[1], acc[oo]);
            acc[oo] = fmaf(x2, wr[2], acc[oo]);
        }
    }
    const size_t obase = (size_t)b * 8192 + t;
    if (!LIP) {
        #pragma unroll
        for (int oo = 0; oo < 8; ++oo)
            yraw_out[obase + (size_t)oo * 1024] = acc[oo] + bias[oo];
    } else {
        float lpart = 0.f;
        #pragma unroll
        for (int oo = 0; oo < 8; ++oo) {
            const float d = (acc[oo] + bias[oo]) - yraw_ref[obase + (size_t)oo * 1024];
            lpart = fmaf(d, d, lpart);
        }
        const float tot = blockReduceSum256(lpart, red);
        if (threadIdx.x == 0) atomicAdd(lip_acc, tot);
    }
}

// ---------------- VQ ----------------
// grid (B, 8 code-tiles). thread = k. z[b,:,k] in regs; codebook via uniform s_loads.
__global__ __launch_bounds__(256)
void vq_dist_kernel(const float* __restrict__ z, const float* __restrict__ cb,
                    const float* __restrict__ cnorm,
                    float* __restrict__ pbest, int* __restrict__ pidx) {
    const int b = blockIdx.x;
    const int tile = blockIdx.y;
    const int k = threadIdx.x;
    float zr[64];
    #pragma unroll
    for (int d = 0; d < 64; ++d) zr[d] = z[((size_t)(b * 64 + d)) * 256 + k];
    const float4* __restrict__ cb4 =
        reinterpret_cast<const float4*>(cb) + (size_t)tile * 64 * 16;
    float best = FLT_MAX; int bi = 0;
    #pragma unroll 2
    for (int e = 0; e < 64; ++e) {
        float d0 = 0.f, d1 = 0.f, d2 = 0.f, d3 = 0.f;
        #pragma unroll
        for (int q = 0; q < 16; ++q) {
            const float4 c4 = cb4[e * 16 + q];    // uniform -> s_load_dwordx4
            d0 = fmaf(zr[4 * q + 0], c4.x, d0);
            d1 = fmaf(zr[4 * q + 1], c4.y, d1);
            d2 = fmaf(zr[4 * q + 2], c4.z, d2);
            d3 = fmaf(zr[4 * q + 3], c4.w, d3);
        }
        const float dist = cnorm[tile * 64 + e] - 2.f * ((d0 + d1) + (d2 + d3));
        if (dist < best) { best = dist; bi = tile * 64 + e; }  // strict < : first-min
    }
    pbest[((size_t)tile * 64 + b) * 256 + k] = best;
    pidx [((size_t)tile * 64 + b) * 256 + k] = bi;
}

// combine tiles; grid (B, 4): each block handles 16 d's. chunk 0 writes codes.
__global__ __launch_bounds__(256)
void vq_combine_kernel(const float* __restrict__ z, const float* __restrict__ cb,
                       const float* __restrict__ pbest, const int* __restrict__ pidx,
                       const float* __restrict__ nz,
                       int* __restrict__ codes, float* __restrict__ zq,
                       float* __restrict__ zq2, float* __restrict__ vq_acc) {
    const int b = blockIdx.x;
    const int dc = blockIdx.y * 16;
    const int k = threadIdx.x;
    __shared__ float red[4];
    float best = FLT_MAX; int bi = 0;
    #pragma unroll
    for (int tile = 0; tile < 8; ++tile) {
        const float v = pbest[((size_t)tile * 64 + b) * 256 + k];
        const int   i = pidx [((size_t)tile * 64 + b) * 256 + k];
        if (v < best) { best = v; bi = i; }  // ascending tiles -> first-min
    }
    if (blockIdx.y == 0) codes[b * 256 + k] = bi;
    const float* __restrict__ cw = cb + (size_t)bi * 64;
    float part = 0.f;
    #pragma unroll
    for (int dd = 0; dd < 16; ++dd) {
        const int d = dc + dd;
        const size_t loc = ((size_t)(b * 64 + d)) * 256 + k;
        const float c = cw[d];                 // divergent gather
        const float zv = z[loc];               // read before aliased zq2 write
        zq[loc] = c;
        zq2[loc] = fmaf(0.01f, nz[loc], c);
        const float df = c - zv;
        part = fmaf(df, df, part);
    }
    const float tot = blockReduceSum256(part, red);
    if (threadIdx.x == 0) atomicAdd(vq_acc, tot);
}

// ---------------- softmax over length dim ----------------
__global__ __launch_bounds__(256)
void softmax_kernel(const float* __restrict__ yraw, float* __restrict__ y) {
    const int bc = blockIdx.x;
    const float* __restrict__ r = yraw + (size_t)bc * 1024;
    float* __restrict__ o = y + (size_t)bc * 1024;
    __shared__ float buf[4];
    float v[4];
    float mx = -FLT_MAX;
    #pragma unroll
    for (int j = 0; j < 4; ++j) { v[j] = r[threadIdx.x + 256 * j]; mx = fmaxf(mx, v[j]); }
    #pragma unroll
    for (int m = 32; m > 0; m >>= 1) mx = fmaxf(mx, __shfl_xor(mx, m, 64));
    if ((threadIdx.x & 63) == 0) buf[threadIdx.x >> 6] = mx;
    __syncthreads();
    mx = fmaxf(fmaxf(buf[0], buf[1]), fmaxf(buf[2], buf[3]));
    __syncthreads();
    float e[4]; float s = 0.f;
    #pragma unroll
    for (int j = 0; j < 4; ++j) { e[j] = expf(v[j] - mx); s += e[j]; }
    #pragma unroll
    for (int m = 32; m > 0; m >>= 1) s += __shfl_xor(s, m, 64);
    if ((threadIdx.x & 63) == 0) buf[threadIdx.x >> 6] = s;
    __syncthreads();
    s = (buf[0] + buf[1]) + (buf[2] + buf[3]);
    #pragma unroll
    for (int j = 0; j < 4; ++j) o[threadIdx.x + 256 * j] = e[j] / s;
}

// ---------------- lv branch: partials over quarters ----------------
__global__ __launch_bounds__(256)
void lv_kernel(const float* __restrict__ h2, const float* __restrict__ wlv,
               float* __restrict__ lvp) {
    const int b = blockIdx.x, zz = blockIdx.y;
    __shared__ float red[4];
    const float4* __restrict__ hb =
        reinterpret_cast<const float4*>(h2 + (size_t)b * 65536) + (size_t)zz * 4096;
    float s = 0.f;
    for (int i = threadIdx.x; i < 4096; i += 256) {
        const float4 v = hb[i];
        const float wc = wlv[(zz * 4096 + i) >> 8];   // uniform per iteration
        s = fmaf((v.x + v.y) + (v.z + v.w), wc, s);
    }
    const float tot = blockReduceSum256(s, red);
    if (threadIdx.x == 0) lvp[zz * 64 + b] = tot;
}

// ---------------- crv branch ----------------
__global__ __launch_bounds__(256)
void dist_kernel(const float* __restrict__ y, float* __restrict__ dist) {
    const int j = blockIdx.x, i = blockIdx.y;
    if (i > j) return;
    __shared__ float red[4];
    const float4* __restrict__ yi = reinterpret_cast<const float4*>(y + (size_t)i * 8192);
    const float4* __restrict__ yj = reinterpret_cast<const float4*>(y + (size_t)j * 8192);
    float s = 0.f;
    for (int e = threadIdx.x; e < 2048; e += 256) {
        const float4 a = yi[e], c = yj[e];
        const float d0 = a.x - c.x, d1 = a.y - c.y, d2 = a.z - c.z, d3 = a.w - c.w;
        s = fmaf(d0, d0, s); s = fmaf(d1, d1, s);
        s = fmaf(d2, d2, s); s = fmaf(d3, d3, s);
    }
    const float tot = blockReduceSum256(s, red);
    if (threadIdx.x == 0) {
        const float v = tot * (1.f / 8192.f);
        dist[i * 64 + j] = v;
        dist[j * 64 + i] = v;
    }
}

__global__ __launch_bounds__(256)
void crv_kernel(const int* __restrict__ codes, const float* __restrict__ dist,
                float* __restrict__ crv_acc) {
    const int kk = blockIdx.x;
    __shared__ int ck[64];
    __shared__ float red[4];
    if (threadIdx.x < 64) ck[threadIdx.x] = codes[threadIdx.x * 256 + kk];
    __syncthreads();
    float sn = 0.f, sd = 0.f;
    for (int idx = threadIdx.x; idx < 4096; idx += 256) {
        const int i = idx >> 6, j = idx & 63;
        if (ck[i] == ck[j]) { sn += dist[idx]; sd += 1.f; }
    }
    const float tn = blockReduceSum256(sn, red);
    const float td = blockReduceSum256(sd, red);
    if (threadIdx.x == 0) atomicAdd(crv_acc, tn / (td + 1e-6f));
}

// ---------------- finalize: lv_loss grid + scalars ----------------
__global__ __launch_bounds__(256)
void final_kernel(const float* __restrict__ tgt, const float* __restrict__ lvp,
                  const float* __restrict__ blv, const float* __restrict__ acc,
                  float* __restrict__ out) {
    const int idx = blockIdx.x * 256 + threadIdx.x; // 4096
    const int i = idx >> 6, j = idx & 63;
    const float lvj = ((lvp[j] + lvp[64 + j]) + (lvp[128 + j] + lvp[192 + j]))
                      * (1.f / 1024.f) + blv[0];
    const float d = tgt[i] - lvj;
    out[OUT_LV + idx] = d * d;
    if (idx == 0) {
        out[528384] = 0.25f * acc[0] * (1.f / 1048576.f);            // vq_loss
        const float lip = acc[1] * (1.f / 524288.f) * 1e4f;          // /EPS^2
        const float crv = acc[2] * (1.f / 256.f);
        out[528385] = lip + crv;                                     // smoothness
    }
}

// ---------------- launch ----------------
extern "C" void kernel_launch(void* const* d_in, const int* in_sizes, int n_in,
                              void* d_out, int out_size, void* d_ws, size_t ws_size,
                              hipStream_t stream) {
    const float* x   = (const float*)d_in[0];
    const float* We1 = (const float*)d_in[1];
    const float* be1 = (const float*)d_in[2];
    const float* We2 = (const float*)d_in[3];
    const float* be2 = (const float*)d_in[4];
    const float* We3 = (const float*)d_in[5];
    const float* be3 = (const float*)d_in[6];
    const float* Wd1 = (const float*)d_in[7];
    const float* bd1 = (const float*)d_in[8];
    const float* Wd2 = (const float*)d_in[9];
    const float* bd2 = (const float*)d_in[10];
    const float* Wd3 = (const float*)d_in[11];
    const float* bd3 = (const float*)d_in[12];
    const float* cb  = (const float*)d_in[13];
    const float* Wlv = (const float*)d_in[14];
    const float* blv = (const float*)d_in[15];
    const float* nz  = (const float*)d_in[16];
    float* out = (float*)d_out;
    float* ws  = (float*)d_ws;

    float* cnorm = ws + F_CN;
    float* lvp   = ws + F_LVP;
    float* tgt   = ws + F_TGT;
    float* acc   = ws + F_ACC;
    int*   codes = (int*)(ws + F_CODES);
    float* dist  = ws + F_DIST;
    float* pbest = ws + F_PBEST;
    int*   pidx  = (int*)(ws + F_PIDX);

    float* yraw = ws + B_YRAW;
    float* zq   = ws + B_ZQ;
    float* z    = ws + B_Z;                  // z, then zq2 in-place
    float* h2d  = ws + B_H2;
    float* big  = ws + B_BIG;
    float* h1e  = big;
    float* h2e  = big + 2097152;

    preamble_kernel<<<67, 256, 0, stream>>>(x, cb, cnorm, tgt, acc);

    // encoder (grid.x = b for XCD-local L2 reuse)
    conv_s2k4_sg<8, 1024, 512, 8, 4, true><<<dim3(64, 8, 2), 128, 0, stream>>>(x, We1, be1, h1e);
    conv_s2k4_sg<64, 512, 256, 8, 4, true><<<dim3(64, 16, 1), 128, 0, stream>>>(h1e, We2, be2, h2e);
    conv_s1k3_sg<128, 256, 8, 2, false><<<dim3(64, 8, 1), 128, 0, stream>>>(h2e, We3, be3, z);

    // VQ (emits zq and zq2 = zq + 0.01*noise; zq2 overwrites z in-place)
    vq_dist_kernel<<<dim3(64, 8), 256, 0, stream>>>(z, cb, cnorm, pbest, pidx);
    vq_combine_kernel<<<dim3(64, 4), 256, 0, stream>>>(z, cb, pbest, pidx, nz,
                                                       codes, zq, z, &acc[0]);

    // decoder pass 1 (clean)
    convT_sg<64, 256, 8, 4, true><<<dim3(64, 16, 1), 128, 0, stream>>>(zq, Wd1, bd1, big);
    convT_sg<128, 512, 8, 2, true><<<dim3(64, 8, 2), 128, 0, stream>>>(big, Wd2, bd2, h2d);
    convd3_sg<false><<<dim3(64, 4), 256, 0, stream>>>(h2d, Wd3, bd3, yraw, nullptr, nullptr);
    softmax_kernel<<<512, 256, 0, stream>>>(yraw, out);
    lv_kernel<<<dim3(64, 4), 256, 0, stream>>>(h2d, Wlv, lvp);

    // decoder pass 2 (perturbed)
    convT_sg<64, 256, 8, 4, true><<<dim3(64, 16, 1), 128, 0, stream>>>(z, Wd1, bd1, big);
    convT_sg<128, 512, 8, 2, true><<<dim3(64, 8, 2), 128, 0, stream>>>(big, Wd2, bd2, h2d);
    convd3_sg<true><<<dim3(64, 4), 256, 0, stream>>>(h2d, Wd3, bd3, nullptr, yraw, &acc[1]);

    // crv branch + outputs
    dist_kernel<<<dim3(64, 64), 256, 0, stream>>>(out, dist);
    crv_kernel<<<256, 256, 0, stream>>>(codes, dist, &acc[2]);
    final_kernel<<<16, 256, 0, stream>>>(tgt, lvp, blv, acc, out);
}

// Round 8
// 394.809 us; speedup vs baseline: 1.1633x; 1.0849x over previous
//
#include <hip/hip_runtime.h>
#include <float.h>
#include <math.h>

#define DEV_INLINE __device__ __forceinline__

// ---------------- problem constants ----------------
// B=64, C_IN=8, L=1024, D=64, K=256, E=512, BETA=0.25, EPS_LIP=0.01

// ---------------- ws layout (float offsets) ----------------
static constexpr size_t F_CN    = 0;       // 512   : |c_e|^2
static constexpr size_t F_LVP   = 512;     // 256   : lv partials [4][B]
static constexpr size_t F_TGT   = 768;     // 64    : log-sum targets
static constexpr size_t F_ACC   = 832;     // 16    : [0]=vq [1]=lip [2]=crv
static constexpr size_t F_CODES = 848;     // 16384 : codes [B][K] (int)
static constexpr size_t F_DIST  = 17232;   // 4096  : dist [B][B]
static constexpr size_t F_PBEST = 21328;   // 131072: per-tile best dist [8][B][K]
static constexpr size_t F_PIDX  = 152400;  // 131072: per-tile best idx (int)

static constexpr size_t B_YRAW = 283472;   // 524288 : y_raw [64][8][1024]
static constexpr size_t B_ZQ   = 807760;   // 1048576: zq
static constexpr size_t B_Z    = 1856336;  // 1048576: z, then zq2 in-place
static constexpr size_t B_H2   = 2904912;  // 4194304: h2 [64][64][1024]
static constexpr size_t B_BIG  = 7099216;  // 4194304: h1e|h2e (enc), then dec h1
// total 11,293,520 floats = ~45.2 MB

// out layout: y [64*8*1024] | lv_loss [64*64] | vq_loss | smoothness
static constexpr size_t OUT_LV = 524288;

// ---------------- reduction helpers ----------------
DEV_INLINE float waveReduceSum(float v) {
    #pragma unroll
    for (int m = 32; m > 0; m >>= 1) v += __shfl_xor(v, m, 64);
    return v;
}

DEV_INLINE float blockReduceSum256(float v, float* buf) {
    __syncthreads();
    v = waveReduceSum(v);
    if ((threadIdx.x & 63) == 0) buf[threadIdx.x >> 6] = v;
    __syncthreads();
    return (buf[0] + buf[1]) + (buf[2] + buf[3]);
}

// ---------------- preamble: acc zero + cnorm + tgt ----------------
__global__ __launch_bounds__(256)
void preamble_kernel(const float* __restrict__ x, const float* __restrict__ cb,
                     float* __restrict__ cnorm, float* __restrict__ tgt,
                     float* __restrict__ acc) {
    const int blk = blockIdx.x;
    if (blk < 64) {
        __shared__ float red[4];
        const float* __restrict__ xb = x + (size_t)blk * 8 * 1024;
        float s = 0.f;
        for (int t = threadIdx.x; t < 1024; t += 256) s += xb[t];
        const float tot = blockReduceSum256(s, red);
        if (threadIdx.x == 0) tgt[blk] = logf(tot + 1e-7f);
    } else if (blk < 66) {
        const int e = (blk - 64) * 256 + threadIdx.x;
        const float* __restrict__ c = cb + (size_t)e * 64;
        float s = 0.f;
        #pragma unroll
        for (int d = 0; d < 64; ++d) s = fmaf(c[d], c[d], s);
        cnorm[e] = s;
    } else {
        if (threadIdx.x < 16) acc[threadIdx.x] = 0.f;
    }
}

// ---------------- conv kernels: SGPR weights, aligned vector loads ----------------
// XCD note: blockIdx.x = b everywhere -> batch-local blocks colocate on one XCD L2.
// All grids use gridDim.z == 1; thread gid covers the full length dimension.

// stride-2 k=4 pad=1. TE output positions/thread. grid (B, Cout/OG, 1), THR threads.
// out[t] = sum_i sum_dk w[o][i][dk] * x[i][2t-1+dk], t = TE*gid + j
// xs[0]=x[2t0-1], xs[1+m]=x[2t0+m] (m<2TE), xs[2TE+1]=x[2t0+2TE]; out j uses xs[2j..2j+3]
template<int CIN, int LIN, int LOUT, int OG, int TE, int UNR, bool RELU, int THR>
__global__ __launch_bounds__(THR)
void conv_s2k4_v(const float* __restrict__ in, const float* __restrict__ w,
                 const float* __restrict__ bias, float* __restrict__ out) {
    const int b  = blockIdx.x;
    const int og = blockIdx.y;
    const int gid = threadIdx.x;                     // 0..LOUT/TE-1
    const int t0 = TE * gid;
    const float* __restrict__ inb = in + (size_t)b * CIN * LIN;
    const float4* __restrict__ wg = reinterpret_cast<const float4*>(w) + (size_t)og * OG * CIN;
    float acc[OG][TE];
    #pragma unroll
    for (int oo = 0; oo < OG; ++oo)
        #pragma unroll
        for (int j = 0; j < TE; ++j) acc[oo][j] = 0.f;
    const bool vm = (gid > 0);
    const bool vp = (2 * t0 + 2 * TE < LIN);
    const int qm = vm ? 2 * t0 - 1 : 0;
    const int qp = vp ? 2 * t0 + 2 * TE : 0;
    #pragma unroll UNR
    for (int i = 0; i < CIN; ++i) {
        const float* __restrict__ row = inb + (size_t)i * LIN;
        float xs[2 * TE + 2];
        {
            float v = row[qm]; xs[0] = vm ? v : 0.f;
        }
        #pragma unroll
        for (int q = 0; q < TE / 2; ++q) {           // TE/2 float4 loads (2*TE floats)
            const float4 v4 = *reinterpret_cast<const float4*>(row + 2 * t0 + 4 * q);
            xs[1 + 4 * q] = v4.x; xs[2 + 4 * q] = v4.y;
            xs[3 + 4 * q] = v4.z; xs[4 + 4 * q] = v4.w;
        }
        {
            float v = row[qp]; xs[2 * TE + 1] = vp ? v : 0.f;
        }
        #pragma unroll
        for (int oo = 0; oo < OG; ++oo) {
            const float4 wv = wg[oo * CIN + i];      // uniform -> s_load_dwordx4
            #pragma unroll
            for (int j = 0; j < TE; ++j) {
                acc[oo][j] = fmaf(xs[2 * j + 0], wv.x, acc[oo][j]);
                acc[oo][j] = fmaf(xs[2 * j + 1], wv.y, acc[oo][j]);
                acc[oo][j] = fmaf(xs[2 * j + 2], wv.z, acc[oo][j]);
                acc[oo][j] = fmaf(xs[2 * j + 3], wv.w, acc[oo][j]);
            }
        }
    }
    const int Cout = gridDim.y * OG;
    #pragma unroll
    for (int oo = 0; oo < OG; ++oo) {
        const float bb = bias[og * OG + oo];
        float* __restrict__ op = out + ((size_t)b * Cout + og * OG + oo) * LOUT + t0;
        float v[TE];
        #pragma unroll
        for (int j = 0; j < TE; ++j) {
            v[j] = acc[oo][j] + bb;
            if (RELU) v[j] = fmaxf(v[j], 0.f);
        }
        if (TE == 4)
            *reinterpret_cast<float4*>(op) = make_float4(v[0], v[1], v[2], v[3]);
        else
            *reinterpret_cast<float2*>(op) = make_float2(v[0], v[1]);
    }
}

// stride-1 k=3 pad=1. TE outputs/thread. grid (B, Cout/OG, 1), THR threads.
// xs[0]=x[t0-1], xs[1+m]=x[t0+m] (m<TE), xs[TE+1]=x[t0+TE]; out j uses xs[j..j+2]
template<int CIN, int LIN, int OG, int TE, int UNR, bool RELU, int THR>
__global__ __launch_bounds__(THR)
void conv_s1k3_v(const float* __restrict__ in, const float* __restrict__ w,
                 const float* __restrict__ bias, float* __restrict__ out) {
    const int b  = blockIdx.x;
    const int og = blockIdx.y;
    const int gid = threadIdx.x;                     // 0..LIN/TE-1
    const int t0 = TE * gid;
    const float* __restrict__ inb = in + (size_t)b * CIN * LIN;
    float acc[OG][TE];
    #pragma unroll
    for (int oo = 0; oo < OG; ++oo)
        #pragma unroll
        for (int j = 0; j < TE; ++j) acc[oo][j] = 0.f;
    const bool vm = (gid > 0), vp = (t0 + TE < LIN);
    const int qm = vm ? t0 - 1 : 0, qp = vp ? t0 + TE : 0;
    #pragma unroll UNR
    for (int i = 0; i < CIN; ++i) {
        const float* __restrict__ row = inb + (size_t)i * LIN;
        float xs[TE + 2];
        { float v = row[qm]; xs[0] = vm ? v : 0.f; }
        if (TE == 4) {
            const float4 v4 = *reinterpret_cast<const float4*>(row + t0);
            xs[1] = v4.x; xs[2] = v4.y; xs[3] = v4.z; xs[4] = v4.w;
        } else {
            const float2 v2 = *reinterpret_cast<const float2*>(row + t0);
            xs[1] = v2.x; xs[2] = v2.y;
        }
        { float v = row[qp]; xs[TE + 1] = vp ? v : 0.f; }
        #pragma unroll
        for (int oo = 0; oo < OG; ++oo) {
            const float* __restrict__ wr = w + ((size_t)(og * OG + oo) * CIN + i) * 3;
            const float w0 = wr[0], w1 = wr[1], w2 = wr[2];   // uniform -> s_load
            #pragma unroll
            for (int j = 0; j < TE; ++j) {
                acc[oo][j] = fmaf(xs[j + 0], w0, acc[oo][j]);
                acc[oo][j] = fmaf(xs[j + 1], w1, acc[oo][j]);
                acc[oo][j] = fmaf(xs[j + 2], w2, acc[oo][j]);
            }
        }
    }
    const int Cout = gridDim.y * OG;
    #pragma unroll
    for (int oo = 0; oo < OG; ++oo) {
        const float bb = bias[og * OG + oo];
        float* __restrict__ op = out + ((size_t)b * Cout + og * OG + oo) * LIN + t0;
        float v[TE];
        #pragma unroll
        for (int j = 0; j < TE; ++j) {
            v[j] = acc[oo][j] + bb;
            if (RELU) v[j] = fmaxf(v[j], 0.f);
        }
        if (TE == 4)
            *reinterpret_cast<float4*>(op) = make_float4(v[0], v[1], v[2], v[3]);
        else
            *reinterpret_cast<float2*>(op) = make_float2(v[0], v[1]);
    }
}

// ConvTranspose1d (k=4,s=2,p=1) gather. TE te-positions/thread -> 2*TE outputs/ch.
// grid (B, Cout/OG, 1), THR threads.
// t=2te: x[te-1]*w0 + x[te]*w2 ; t=2te+1: x[te]*w1 + x[te+1]*w3
// xs[0]=x[te0-1], xs[1+m]=x[te0+m] (m<TE), xs[TE+1]=x[te0+TE]
template<int CIN, int LIN, int OG, int TE, int UNR, bool RELU, int THR>
__global__ __launch_bounds__(THR)
void convT_v(const float* __restrict__ in, const float* __restrict__ w,
             const float* __restrict__ bias, float* __restrict__ out) {
    const int b  = blockIdx.x;
    const int og = blockIdx.y;
    const int gid = threadIdx.x;                     // 0..LIN/TE-1
    const int te0 = TE * gid;
    const float* __restrict__ inb = in + (size_t)b * CIN * LIN;
    const float4* __restrict__ wg = reinterpret_cast<const float4*>(w) + (size_t)og * OG * CIN;
    float acc[OG][2 * TE];
    #pragma unroll
    for (int oo = 0; oo < OG; ++oo)
        #pragma unroll
        for (int j = 0; j < 2 * TE; ++j) acc[oo][j] = 0.f;
    const bool vm = (gid > 0), vp = (te0 + TE < LIN);
    const int qm = vm ? te0 - 1 : 0, qp = vp ? te0 + TE : 0;
    #pragma unroll UNR
    for (int i = 0; i < CIN; ++i) {
        const float* __restrict__ row = inb + (size_t)i * LIN;
        float xs[TE + 2];
        { float v = row[qm]; xs[0] = vm ? v : 0.f; }
        if (TE == 4) {
            const float4 v4 = *reinterpret_cast<const float4*>(row + te0);
            xs[1] = v4.x; xs[2] = v4.y; xs[3] = v4.z; xs[4] = v4.w;
        } else {
            const float2 v2 = *reinterpret_cast<const float2*>(row + te0);
            xs[1] = v2.x; xs[2] = v2.y;
        }
        { float v = row[qp]; xs[TE + 1] = vp ? v : 0.f; }
        #pragma unroll
        for (int oo = 0; oo < OG; ++oo) {
            const float4 wv = wg[oo * CIN + i];      // uniform -> s_load_dwordx4
            #pragma unroll
            for (int j = 0; j < TE; ++j) {
                acc[oo][2 * j]     = fmaf(xs[j],     wv.x, acc[oo][2 * j]);
                acc[oo][2 * j]     = fmaf(xs[j + 1], wv.z, acc[oo][2 * j]);
                acc[oo][2 * j + 1] = fmaf(xs[j + 1], wv.y, acc[oo][2 * j + 1]);
                acc[oo][2 * j + 1] = fmaf(xs[j + 2], wv.w, acc[oo][2 * j + 1]);
            }
        }
    }
    const int Cout = gridDim.y * OG;
    #pragma unroll
    for (int oo = 0; oo < OG; ++oo) {
        const float bb = bias[og * OG + oo];
        float v[2 * TE];
        #pragma unroll
        for (int j = 0; j < 2 * TE; ++j) {
            v[j] = acc[oo][j] + bb;
            if (RELU) v[j] = fmaxf(v[j], 0.f);
        }
        float* __restrict__ op = out + ((size_t)b * Cout + og * OG + oo) * (2 * LIN) + 2 * te0;
        #pragma unroll
        for (int q = 0; q < TE / 2; ++q)
            *reinterpret_cast<float4*>(op + 4 * q) =
                make_float4(v[4 * q], v[4 * q + 1], v[4 * q + 2], v[4 * q + 3]);
    }
}

// final conv (64->8, k=3, s=1, p=1), all 8 out channels, SGPR weights.
// grid (B, 4), 256 thr. LIP=true: accumulate (y2 - yref)^2 instead of storing.
template<bool LIP>
__global__ __launch_bounds__(256)
void convd3_sg(const float* __restrict__ in, const float* __restrict__ w,
               const float* __restrict__ bias, float* __restrict__ yraw_out,
               const float* __restrict__ yraw_ref, float* __restrict__ lip_acc) {
    const int b = blockIdx.x;
    const int t = blockIdx.y * 256 + threadIdx.x;
    __shared__ float red[4];
    const float* __restrict__ inb = in + (size_t)b * 65536;
    float acc[8];
    #pragma unroll
    for (int oo = 0; oo < 8; ++oo) acc[oo] = 0.f;
    const bool vl = (t > 0), vr = (t < 1023);
    const int ql = vl ? t - 1 : 0, qr = vr ? t + 1 : 0;
    #pragma unroll 2
    for (int i = 0; i < 64; ++i) {
        const float* __restrict__ row = inb + (size_t)i * 1024;
        float x0 = row[ql]; x0 = vl ? x0 : 0.f;
        const float x1 = row[t];
        float x2 = row[qr]; x2 = vr ? x2 : 0.f;
        #pragma unroll
        for (int oo = 0; oo < 8; ++oo) {
            const float* __restrict__ wr = w + ((size_t)oo * 64 + i) * 3;
            acc[oo] = fmaf(x0, wr[0], acc[oo]);
            acc[oo] = fmaf(x1, wr[1], acc[oo]);
            acc[oo] = fmaf(x2, wr[2], acc[oo]);
        }
    }
    const size_t obase = (size_t)b * 8192 + t;
    if (!LIP) {
        #pragma unroll
        for (int oo = 0; oo < 8; ++oo)
            yraw_out[obase + (size_t)oo * 1024] = acc[oo] + bias[oo];
    } else {
        float lpart = 0.f;
        #pragma unroll
        for (int oo = 0; oo < 8; ++oo) {
            const float d = (acc[oo] + bias[oo]) - yraw_ref[obase + (size_t)oo * 1024];
            lpart = fmaf(d, d, lpart);
        }
        const float tot = blockReduceSum256(lpart, red);
        if (threadIdx.x == 0) atomicAdd(lip_acc, tot);
    }
}

// ---------------- VQ ----------------
// grid (B, 8 code-tiles). thread = k. z[b,:,k] in regs; codebook via uniform s_loads.
__global__ __launch_bounds__(256)
void vq_dist_kernel(const float* __restrict__ z, const float* __restrict__ cb,
                    const float* __restrict__ cnorm,
                    float* __restrict__ pbest, int* __restrict__ pidx) {
    const int b = blockIdx.x;
    const int tile = blockIdx.y;
    const int k = threadIdx.x;
    float zr[64];
    #pragma unroll
    for (int d = 0; d < 64; ++d) zr[d] = z[((size_t)(b * 64 + d)) * 256 + k];
    const float4* __restrict__ cb4 =
        reinterpret_cast<const float4*>(cb) + (size_t)tile * 64 * 16;
    float best = FLT_MAX; int bi = 0;
    #pragma unroll 2
    for (int e = 0; e < 64; ++e) {
        float d0 = 0.f, d1 = 0.f, d2 = 0.f, d3 = 0.f;
        #pragma unroll
        for (int q = 0; q < 16; ++q) {
            const float4 c4 = cb4[e * 16 + q];    // uniform -> s_load_dwordx4
            d0 = fmaf(zr[4 * q + 0], c4.x, d0);
            d1 = fmaf(zr[4 * q + 1], c4.y, d1);
            d2 = fmaf(zr[4 * q + 2], c4.z, d2);
            d3 = fmaf(zr[4 * q + 3], c4.w, d3);
        }
        const float dist = cnorm[tile * 64 + e] - 2.f * ((d0 + d1) + (d2 + d3));
        if (dist < best) { best = dist; bi = tile * 64 + e; }  // strict < : first-min
    }
    pbest[((size_t)tile * 64 + b) * 256 + k] = best;
    pidx [((size_t)tile * 64 + b) * 256 + k] = bi;
}

// combine tiles; grid (B, 4): each block handles 16 d's. chunk 0 writes codes.
__global__ __launch_bounds__(256)
void vq_combine_kernel(const float* __restrict__ z, const float* __restrict__ cb,
                       const float* __restrict__ pbest, const int* __restrict__ pidx,
                       const float* __restrict__ nz,
                       int* __restrict__ codes, float* __restrict__ zq,
                       float* __restrict__ zq2, float* __restrict__ vq_acc) {
    const int b = blockIdx.x;
    const int dc = blockIdx.y * 16;
    const int k = threadIdx.x;
    __shared__ float red[4];
    float best = FLT_MAX; int bi = 0;
    #pragma unroll
    for (int tile = 0; tile < 8; ++tile) {
        const float v = pbest[((size_t)tile * 64 + b) * 256 + k];
        const int   i = pidx [((size_t)tile * 64 + b) * 256 + k];
        if (v < best) { best = v; bi = i; }  // ascending tiles -> first-min
    }
    if (blockIdx.y == 0) codes[b * 256 + k] = bi;
    const float* __restrict__ cw = cb + (size_t)bi * 64;
    float part = 0.f;
    #pragma unroll
    for (int dd = 0; dd < 16; ++dd) {
        const int d = dc + dd;
        const size_t loc = ((size_t)(b * 64 + d)) * 256 + k;
        const float c = cw[d];                 // divergent gather
        const float zv = z[loc];               // read before aliased zq2 write
        zq[loc] = c;
        zq2[loc] = fmaf(0.01f, nz[loc], c);
        const float df = c - zv;
        part = fmaf(df, df, part);
    }
    const float tot = blockReduceSum256(part, red);
    if (threadIdx.x == 0) atomicAdd(vq_acc, tot);
}

// ---------------- softmax over length dim ----------------
__global__ __launch_bounds__(256)
void softmax_kernel(const float* __restrict__ yraw, float* __restrict__ y) {
    const int bc = blockIdx.x;
    const float* __restrict__ r = yraw + (size_t)bc * 1024;
    float* __restrict__ o = y + (size_t)bc * 1024;
    __shared__ float buf[4];
    float v[4];
    float mx = -FLT_MAX;
    #pragma unroll
    for (int j = 0; j < 4; ++j) { v[j] = r[threadIdx.x + 256 * j]; mx = fmaxf(mx, v[j]); }
    #pragma unroll
    for (int m = 32; m > 0; m >>= 1) mx = fmaxf(mx, __shfl_xor(mx, m, 64));
    if ((threadIdx.x & 63) == 0) buf[threadIdx.x >> 6] = mx;
    __syncthreads();
    mx = fmaxf(fmaxf(buf[0], buf[1]), fmaxf(buf[2], buf[3]));
    __syncthreads();
    float e[4]; float s = 0.f;
    #pragma unroll
    for (int j = 0; j < 4; ++j) { e[j] = expf(v[j] - mx); s += e[j]; }
    #pragma unroll
    for (int m = 32; m > 0; m >>= 1) s += __shfl_xor(s, m, 64);
    if ((threadIdx.x & 63) == 0) buf[threadIdx.x >> 6] = s;
    __syncthreads();
    s = (buf[0] + buf[1]) + (buf[2] + buf[3]);
    #pragma unroll
    for (int j = 0; j < 4; ++j) o[threadIdx.x + 256 * j] = e[j] / s;
}

// ---------------- lv branch: partials over quarters ----------------
__global__ __launch_bounds__(256)
void lv_kernel(const float* __restrict__ h2, const float* __restrict__ wlv,
               float* __restrict__ lvp) {
    const int b = blockIdx.x, zz = blockIdx.y;
    __shared__ float red[4];
    const float4* __restrict__ hb =
        reinterpret_cast<const float4*>(h2 + (size_t)b * 65536) + (size_t)zz * 4096;
    float s = 0.f;
    for (int i = threadIdx.x; i < 4096; i += 256) {
        const float4 v = hb[i];
        const float wc = wlv[(zz * 4096 + i) >> 8];   // uniform per iteration
        s = fmaf((v.x + v.y) + (v.z + v.w), wc, s);
    }
    const float tot = blockReduceSum256(s, red);
    if (threadIdx.x == 0) lvp[zz * 64 + b] = tot;
}

// ---------------- crv branch ----------------
__global__ __launch_bounds__(256)
void dist_kernel(const float* __restrict__ y, float* __restrict__ dist) {
    const int j = blockIdx.x, i = blockIdx.y;
    if (i > j) return;
    __shared__ float red[4];
    const float4* __restrict__ yi = reinterpret_cast<const float4*>(y + (size_t)i * 8192);
    const float4* __restrict__ yj = reinterpret_cast<const float4*>(y + (size_t)j * 8192);
    float s = 0.f;
    for (int e = threadIdx.x; e < 2048; e += 256) {
        const float4 a = yi[e], c = yj[e];
        const float d0 = a.x - c.x, d1 = a.y - c.y, d2 = a.z - c.z, d3 = a.w - c.w;
        s = fmaf(d0, d0, s); s = fmaf(d1, d1, s);
        s = fmaf(d2, d2, s); s = fmaf(d3, d3, s);
    }
    const float tot = blockReduceSum256(s, red);
    if (threadIdx.x == 0) {
        const float v = tot * (1.f / 8192.f);
        dist[i * 64 + j] = v;
        dist[j * 64 + i] = v;
    }
}

__global__ __launch_bounds__(256)
void crv_kernel(const int* __restrict__ codes, const float* __restrict__ dist,
                float* __restrict__ crv_acc) {
    const int kk = blockIdx.x;
    __shared__ int ck[64];
    __shared__ float red[4];
    if (threadIdx.x < 64) ck[threadIdx.x] = codes[threadIdx.x * 256 + kk];
    __syncthreads();
    float sn = 0.f, sd = 0.f;
    for (int idx = threadIdx.x; idx < 4096; idx += 256) {
        const int i = idx >> 6, j = idx & 63;
        if (ck[i] == ck[j]) { sn += dist[idx]; sd += 1.f; }
    }
    const float tn = blockReduceSum256(sn, red);
    const float td = blockReduceSum256(sd, red);
    if (threadIdx.x == 0) atomicAdd(crv_acc, tn / (td + 1e-6f));
}

// ---------------- finalize: lv_loss grid + scalars ----------------
__global__ __launch_bounds__(256)
void final_kernel(const float* __restrict__ tgt, const float* __restrict__ lvp,
                  const float* __restrict__ blv, const float* __restrict__ acc,
                  float* __restrict__ out) {
    const int idx = blockIdx.x * 256 + threadIdx.x; // 4096
    const int i = idx >> 6, j = idx & 63;
    const float lvj = ((lvp[j] + lvp[64 + j]) + (lvp[128 + j] + lvp[192 + j]))
                      * (1.f / 1024.f) + blv[0];
    const float d = tgt[i] - lvj;
    out[OUT_LV + idx] = d * d;
    if (idx == 0) {
        out[528384] = 0.25f * acc[0] * (1.f / 1048576.f);            // vq_loss
        const float lip = acc[1] * (1.f / 524288.f) * 1e4f;          // /EPS^2
        const float crv = acc[2] * (1.f / 256.f);
        out[528385] = lip + crv;                                     // smoothness
    }
}

// ---------------- launch ----------------
extern "C" void kernel_launch(void* const* d_in, const int* in_sizes, int n_in,
                              void* d_out, int out_size, void* d_ws, size_t ws_size,
                              hipStream_t stream) {
    const float* x   = (const float*)d_in[0];
    const float* We1 = (const float*)d_in[1];
    const float* be1 = (const float*)d_in[2];
    const float* We2 = (const float*)d_in[3];
    const float* be2 = (const float*)d_in[4];
    const float* We3 = (const float*)d_in[5];
    const float* be3 = (const float*)d_in[6];
    const float* Wd1 = (const float*)d_in[7];
    const float* bd1 = (const float*)d_in[8];
    const float* Wd2 = (const float*)d_in[9];
    const float* bd2 = (const float*)d_in[10];
    const float* Wd3 = (const float*)d_in[11];
    const float* bd3 = (const float*)d_in[12];
    const float* cb  = (const float*)d_in[13];
    const float* Wlv = (const float*)d_in[14];
    const float* blv = (const float*)d_in[15];
    const float* nz  = (const float*)d_in[16];
    float* out = (float*)d_out;
    float* ws  = (float*)d_ws;

    float* cnorm = ws + F_CN;
    float* lvp   = ws + F_LVP;
    float* tgt   = ws + F_TGT;
    float* acc   = ws + F_ACC;
    int*   codes = (int*)(ws + F_CODES);
    float* dist  = ws + F_DIST;
    float* pbest = ws + F_PBEST;
    int*   pidx  = (int*)(ws + F_PIDX);

    float* yraw = ws + B_YRAW;
    float* zq   = ws + B_ZQ;
    float* z    = ws + B_Z;                  // z, then zq2 in-place
    float* h2d  = ws + B_H2;
    float* big  = ws + B_BIG;
    float* h1e  = big;
    float* h2e  = big + 2097152;

    preamble_kernel<<<67, 256, 0, stream>>>(x, cb, cnorm, tgt, acc);

    // encoder (grid.x = b for XCD-local L2 reuse; TE outputs/thread, vector loads)
    conv_s2k4_v<8, 1024, 512, 4, 4, 4, true, 128>
        <<<dim3(64, 16, 1), 128, 0, stream>>>(x, We1, be1, h1e);           // Cout=64
    conv_s2k4_v<64, 512, 256, 4, 4, 2, true, 64>
        <<<dim3(64, 32, 1), 64, 0, stream>>>(h1e, We2, be2, h2e);          // Cout=128
    conv_s1k3_v<128, 256, 4, 4, 2, false, 64>
        <<<dim3(64, 16, 1), 64, 0, stream>>>(h2e, We3, be3, z);            // Cout=64

    // VQ (emits zq and zq2 = zq + 0.01*noise; zq2 overwrites z in-place)
    vq_dist_kernel<<<dim3(64, 8), 256, 0, stream>>>(z, cb, cnorm, pbest, pidx);
    vq_combine_kernel<<<dim3(64, 4), 256, 0, stream>>>(z, cb, pbest, pidx, nz,
                                                       codes, zq, z, &acc[0]);

    // decoder pass 1 (clean)
    convT_v<64, 256, 8, 2, 2, true, 128>
        <<<dim3(64, 16, 1), 128, 0, stream>>>(zq, Wd1, bd1, big);          // Cout=128
    convT_v<128, 512, 4, 4, 2, true, 128>
        <<<dim3(64, 16, 1), 128, 0, stream>>>(big, Wd2, bd2, h2d);         // Cout=64
    convd3_sg<false><<<dim3(64, 4), 256, 0, stream>>>(h2d, Wd3, bd3, yraw, nullptr, nullptr);
    softmax_kernel<<<512, 256, 0, stream>>>(yraw, out);
    lv_kernel<<<dim3(64, 4), 256, 0, stream>>>(h2d, Wlv, lvp);

    // decoder pass 2 (perturbed)
    convT_v<64, 256, 8, 2, 2, true, 128>
        <<<dim3(64, 16, 1), 128, 0, stream>>>(z, Wd1, bd1, big);
    convT_v<128, 512, 4, 4, 2, true, 128>
        <<<dim3(64, 16, 1), 128, 0, stream>>>(big, Wd2, bd2, h2d);
    convd3_sg<true><<<dim3(64, 4), 256, 0, stream>>>(h2d, Wd3, bd3, nullptr, yraw, &acc[1]);

    // crv branch + outputs
    dist_kernel<<<dim3(64, 64), 256, 0, stream>>>(out, dist);
    crv_kernel<<<256, 256, 0, stream>>>(codes, dist, &acc[2]);
    final_kernel<<<16, 256, 0, stream>>>(tgt, lvp, blv, acc, out);
}